// Round 2
// baseline (4938.288 us; speedup 1.0000x reference)
//
#include <hip/hip_runtime.h>
#include <hip/hip_bf16.h>

// Problem constants (fixed by the reference)
#define BATCH 4
#define TSEQ 2048
#define DM 1024
#define NH 16
#define DH 64
#define MROWS (BATCH * TSEQ)  // 8192
#define CHUNK 64
#define LPAD 68  // padded LDS row (floats) to spread banks

// ---------- type helpers ----------
__device__ __forceinline__ float ldf(const float* p) { return *p; }
__device__ __forceinline__ float ldf(const __hip_bfloat16* p) { return __bfloat162float(*p); }
__device__ __forceinline__ void stf(float* p, float v) { *p = v; }
__device__ __forceinline__ void stf(__hip_bfloat16* p, float v) { *p = __float2bfloat16(v); }

// ---------- generic fp32-compute tiled GEMM: C(MxN) = A(MxK) @ B(KxN) ----------
#define BM 64
#define BN 64
#define BK 16

template <typename TA, typename TC>
__global__ __launch_bounds__(256) void gemm_kernel(const TA* __restrict__ A,
                                                   const float* __restrict__ B,
                                                   TC* __restrict__ C,
                                                   int M, int N, int K) {
    __shared__ float As[BK][BM + 1];
    __shared__ float Bs[BK][BN + 1];
    const int tid = threadIdx.x;
    const int tr = tid / 16;
    const int tc = tid % 16;
    const int rowBase = blockIdx.y * BM;
    const int colBase = blockIdx.x * BN;

    float acc[4][4];
#pragma unroll
    for (int m = 0; m < 4; ++m)
#pragma unroll
        for (int n = 0; n < 4; ++n) acc[m][n] = 0.f;

    for (int k0 = 0; k0 < K; k0 += BK) {
#pragma unroll
        for (int i = tid; i < BM * BK; i += 256) {
            int r = i / BK, c = i % BK;
            As[c][r] = ldf(&A[(size_t)(rowBase + r) * K + k0 + c]);
        }
#pragma unroll
        for (int i = tid; i < BK * BN; i += 256) {
            int r = i / BN, c = i % BN;
            Bs[r][c] = B[(size_t)(k0 + r) * N + colBase + c];
        }
        __syncthreads();
#pragma unroll
        for (int kk = 0; kk < BK; ++kk) {
            float a[4], b[4];
#pragma unroll
            for (int m = 0; m < 4; ++m) a[m] = As[kk][tr * 4 + m];
#pragma unroll
            for (int n = 0; n < 4; ++n) b[n] = Bs[kk][tc * 4 + n];
#pragma unroll
            for (int m = 0; m < 4; ++m)
#pragma unroll
                for (int n = 0; n < 4; ++n) acc[m][n] += a[m] * b[n];
        }
        __syncthreads();
    }
#pragma unroll
    for (int m = 0; m < 4; ++m)
#pragma unroll
        for (int n = 0; n < 4; ++n)
            stf(&C[(size_t)(rowBase + tr * 4 + m) * N + colBase + tc * 4 + n], acc[m][n]);
}

// ---------- beta = sigmoid(x @ Wbeta + b_beta) ----------
__global__ __launch_bounds__(256) void beta_kernel(const float* __restrict__ x,
                                                   const float* __restrict__ Wb,
                                                   const float* __restrict__ bb,
                                                   float* __restrict__ beta) {
    const int tid = threadIdx.x;
    const int h = tid % NH;
    const int rl = tid / NH;
    const int row = blockIdx.x * 16 + rl;
    const float* xr = x + (size_t)row * DM;
    float acc = 0.f;
#pragma unroll 8
    for (int k = 0; k < DM; ++k) acc += xr[k] * Wb[k * NH + h];
    acc += bb[h];
    beta[row * NH + h] = 1.f / (1.f + __expf(-acc));
}

// ---------- 4x4 outer-product FMA helper ----------
__device__ __forceinline__ void fma44(float (&acc)[4][4], const float4& a4, const float4& b4) {
    float a[4] = {a4.x, a4.y, a4.z, a4.w};
    float b[4] = {b4.x, b4.y, b4.z, b4.w};
#pragma unroll
    for (int m = 0; m < 4; ++m)
#pragma unroll
        for (int n = 0; n < 4; ++n) acc[m][n] += a[m] * b[n];
}

// ---------- chunked DeltaNet scan (WY form), fp32 ----------
// One block (256 thr) per (b,h). Per chunk of C=64 steps:
//   Kn = rownorm(K); A[t,s] = beta_t (k_t.k_s) (s<t)
//   M  = B(V - Kn W0^T);  solve (I+A) U = M  (forward substitution)
//   O  = Q W0^T + tril(Q Kn^T, incl diag) U;  W0 += U^T Kn
__global__ __launch_bounds__(256) void scan_chunked(const float* __restrict__ Q,
                                                    const float* __restrict__ K,
                                                    const float* __restrict__ V,
                                                    const float* __restrict__ beta,
                                                    float* __restrict__ O) {
    const int bh = blockIdx.x;
    const int b = bh >> 4;
    const int h = bh & 15;
    const int tid = threadIdx.x;
    const int wave = tid >> 6;
    const int lane = tid & 63;
    const int tr = tid >> 4;  // 0..15 (row tile)
    const int tc = tid & 15;  // 0..15 (col tile)
    const int lt = tid >> 2;  // 0..63 loader row
    const int j0 = (tid & 3) * 16;  // loader col quarter

    __shared__ float W0T[DH][LPAD];     // W0T[j][i] = W[i][j]  (state)
    __shared__ float Kn[CHUNK][LPAD];   // [t][j]
    __shared__ float KnT[DH][LPAD];     // [j][t]
    __shared__ float QT[DH][LPAD];      // [j][t]
    __shared__ float U[CHUNK][LPAD];    // [t][i]  (M, then U)
    __shared__ float Am[CHUNK][LPAD];   // [t][s], reused as ST[s][t]
    __shared__ float sbeta[CHUNK];

    for (int idx = tid; idx < DH * DH; idx += 256) W0T[idx >> 6][idx & 63] = 0.f;

    const size_t gstride = NH * DH;  // 1024
    const size_t gbase = (size_t)b * TSEQ * gstride + (size_t)h * DH;

    for (int c0 = 0; c0 < TSEQ; c0 += CHUNK) {
        // ---- load K chunk (L2-normalize rows), Q chunk (transposed), beta ----
        {
            const float4* kp = (const float4*)(K + gbase + (size_t)(c0 + lt) * gstride + j0);
            float4 k0 = kp[0], k1 = kp[1], k2 = kp[2], k3 = kp[3];
            float ss = k0.x * k0.x + k0.y * k0.y + k0.z * k0.z + k0.w * k0.w +
                       k1.x * k1.x + k1.y * k1.y + k1.z * k1.z + k1.w * k1.w +
                       k2.x * k2.x + k2.y * k2.y + k2.z * k2.z + k2.w * k2.w +
                       k3.x * k3.x + k3.y * k3.y + k3.z * k3.z + k3.w * k3.w;
            ss += __shfl_xor(ss, 1);
            ss += __shfl_xor(ss, 2);
            const float rn = 1.f / fmaxf(sqrtf(ss), 1e-12f);
            k0.x *= rn; k0.y *= rn; k0.z *= rn; k0.w *= rn;
            k1.x *= rn; k1.y *= rn; k1.z *= rn; k1.w *= rn;
            k2.x *= rn; k2.y *= rn; k2.z *= rn; k2.w *= rn;
            k3.x *= rn; k3.y *= rn; k3.z *= rn; k3.w *= rn;
            *(float4*)&Kn[lt][j0 + 0] = k0;
            *(float4*)&Kn[lt][j0 + 4] = k1;
            *(float4*)&Kn[lt][j0 + 8] = k2;
            *(float4*)&Kn[lt][j0 + 12] = k3;
            KnT[j0 + 0][lt] = k0.x;  KnT[j0 + 1][lt] = k0.y;
            KnT[j0 + 2][lt] = k0.z;  KnT[j0 + 3][lt] = k0.w;
            KnT[j0 + 4][lt] = k1.x;  KnT[j0 + 5][lt] = k1.y;
            KnT[j0 + 6][lt] = k1.z;  KnT[j0 + 7][lt] = k1.w;
            KnT[j0 + 8][lt] = k2.x;  KnT[j0 + 9][lt] = k2.y;
            KnT[j0 + 10][lt] = k2.z; KnT[j0 + 11][lt] = k2.w;
            KnT[j0 + 12][lt] = k3.x; KnT[j0 + 13][lt] = k3.y;
            KnT[j0 + 14][lt] = k3.z; KnT[j0 + 15][lt] = k3.w;

            const float4* qp = (const float4*)(Q + gbase + (size_t)(c0 + lt) * gstride + j0);
            float4 q0 = qp[0], q1 = qp[1], q2 = qp[2], q3 = qp[3];
            QT[j0 + 0][lt] = q0.x;  QT[j0 + 1][lt] = q0.y;
            QT[j0 + 2][lt] = q0.z;  QT[j0 + 3][lt] = q0.w;
            QT[j0 + 4][lt] = q1.x;  QT[j0 + 5][lt] = q1.y;
            QT[j0 + 6][lt] = q1.z;  QT[j0 + 7][lt] = q1.w;
            QT[j0 + 8][lt] = q2.x;  QT[j0 + 9][lt] = q2.y;
            QT[j0 + 10][lt] = q2.z; QT[j0 + 11][lt] = q2.w;
            QT[j0 + 12][lt] = q3.x; QT[j0 + 13][lt] = q3.y;
            QT[j0 + 14][lt] = q3.z; QT[j0 + 15][lt] = q3.w;

            if (tid < CHUNK)
                sbeta[tid] = beta[((size_t)(b * TSEQ + c0 + tid)) * NH + h];
        }
        __syncthreads();

        // ---- fused matmuls over j: M (into U), Am, QW (into accO regs) ----
        float accO[4][4], accM[4][4], accA[4][4];
#pragma unroll
        for (int m = 0; m < 4; ++m)
#pragma unroll
            for (int n = 0; n < 4; ++n) { accO[m][n] = 0.f; accM[m][n] = 0.f; accA[m][n] = 0.f; }

        float4 vv[4];
#pragma unroll
        for (int m = 0; m < 4; ++m)
            vv[m] = *(const float4*)(V + gbase + (size_t)(c0 + tr * 4 + m) * gstride + tc * 4);

#pragma unroll
        for (int kk = 0; kk < DH; ++kk) {
            float4 aK = *(const float4*)&KnT[kk][tr * 4];
            float4 aQ = *(const float4*)&QT[kk][tr * 4];
            float4 bW = *(const float4*)&W0T[kk][tc * 4];
            float4 bK = *(const float4*)&KnT[kk][tc * 4];
            fma44(accM, aK, bW);  // K W0^T
            fma44(accO, aQ, bW);  // Q W0^T
            fma44(accA, aK, bK);  // K K^T
        }
#pragma unroll
        for (int m = 0; m < 4; ++m) {
            const int r = tr * 4 + m;
            const float bt = sbeta[r];
            const float* vm = (const float*)&vv[m];
#pragma unroll
            for (int n = 0; n < 4; ++n) {
                U[r][tc * 4 + n] = bt * (vm[n] - accM[m][n]);
                Am[r][tc * 4 + n] = bt * accA[m][n];
            }
        }
        __syncthreads();

        // ---- forward substitution: u_t = m_t - sum_{s<t} Am[t][s] u_s (wave 0) ----
        if (wave == 0) {
            float u[CHUNK];
#pragma unroll
            for (int s = 0; s < CHUNK; ++s) u[s] = U[s][lane];
#pragma unroll
            for (int t = 1; t < CHUNK; ++t) {
                float corr = 0.f;
#pragma unroll
                for (int s = 0; s < t; ++s) corr += Am[t][s] * u[s];
                u[t] -= corr;
            }
#pragma unroll
            for (int s = 0; s < CHUNK; ++s) U[s][lane] = u[s];
        }
        __syncthreads();

        // ---- W0 update (W0T[j][i] += sum_t Kn[t][j] U[t][i]) and ST[s][t] ----
        float accW[4][4], accS[4][4];
#pragma unroll
        for (int m = 0; m < 4; ++m)
#pragma unroll
            for (int n = 0; n < 4; ++n) { accW[m][n] = 0.f; accS[m][n] = 0.f; }
#pragma unroll
        for (int kk = 0; kk < CHUNK; ++kk) {
            float4 aN = *(const float4*)&Kn[kk][tr * 4];   // kk=t, r=j
            float4 bU = *(const float4*)&U[kk][tc * 4];    // U[t][i]
            float4 aT = *(const float4*)&KnT[kk][tr * 4];  // kk=j, r=s
            float4 bQ = *(const float4*)&QT[kk][tc * 4];   // QT[j][t]
            fma44(accW, aN, bU);
            fma44(accS, aT, bQ);
        }
#pragma unroll
        for (int m = 0; m < 4; ++m)
#pragma unroll
            for (int n = 0; n < 4; ++n) {
                W0T[tr * 4 + m][tc * 4 + n] += accW[m][n];
                // ST[s][t]: keep s<=t (diag included), else 0
                Am[tr * 4 + m][tc * 4 + n] = (tr * 4 + m <= tc * 4 + n) ? accS[m][n] : 0.f;
            }
        __syncthreads();

        // ---- O = QW + ST^T-applied U; write chunk output ----
#pragma unroll
        for (int kk = 0; kk < CHUNK; ++kk) {
            float4 aS = *(const float4*)&Am[kk][tr * 4];  // ST[s][t], kk=s, r=t
            float4 bU = *(const float4*)&U[kk][tc * 4];
            fma44(accO, aS, bU);
        }
#pragma unroll
        for (int m = 0; m < 4; ++m) {
            float4 o4 = make_float4(accO[m][0], accO[m][1], accO[m][2], accO[m][3]);
            *(float4*)(O + gbase + (size_t)(c0 + tr * 4 + m) * gstride + tc * 4) = o4;
        }
        __syncthreads();
    }
}

// ---------- legacy sequential scan (bf16 fallback path only) ----------
template <typename TS>
__global__ __launch_bounds__(64) void scan_kernel(const TS* __restrict__ Q,
                                                  const TS* __restrict__ K,
                                                  const TS* __restrict__ V,
                                                  const float* __restrict__ beta,
                                                  float* __restrict__ O) {
    const int bh = blockIdx.x;
    const int b = bh >> 4;
    const int h = bh & 15;
    const int lane = threadIdx.x;

    float Wrow[64];
#pragma unroll
    for (int j = 0; j < 64; ++j) Wrow[j] = 0.f;

    __shared__ float sk[64];
    __shared__ float sq[64];

    size_t base = ((size_t)b * TSEQ) * (NH * DH) + h * DH + lane;
    int brow = b * TSEQ;

    for (int t = 0; t < TSEQ; ++t, base += NH * DH) {
        float k = ldf(&K[base]);
        float q = ldf(&Q[base]);
        float v = ldf(&V[base]);
        float be = beta[(size_t)(brow + t) * NH + h];

        float ss = k * k;
#pragma unroll
        for (int off = 32; off > 0; off >>= 1) ss += __shfl_xor(ss, off);
        k = k / fmaxf(sqrtf(ss), 1e-12f);

        sk[lane] = k;
        sq[lane] = q;
        __syncthreads();

        float p0 = 0.f, p1 = 0.f, p2 = 0.f, p3 = 0.f;
#pragma unroll
        for (int j = 0; j < 64; j += 4) {
            p0 += Wrow[j + 0] * sk[j + 0];
            p1 += Wrow[j + 1] * sk[j + 1];
            p2 += Wrow[j + 2] * sk[j + 2];
            p3 += Wrow[j + 3] * sk[j + 3];
        }
        const float bei = be * (v - ((p0 + p1) + (p2 + p3)));

        float o0 = 0.f, o1 = 0.f, o2 = 0.f, o3 = 0.f;
#pragma unroll
        for (int j = 0; j < 64; j += 4) {
            Wrow[j + 0] += bei * sk[j + 0]; o0 += Wrow[j + 0] * sq[j + 0];
            Wrow[j + 1] += bei * sk[j + 1]; o1 += Wrow[j + 1] * sq[j + 1];
            Wrow[j + 2] += bei * sk[j + 2]; o2 += Wrow[j + 2] * sq[j + 2];
            Wrow[j + 3] += bei * sk[j + 3]; o3 += Wrow[j + 3] * sq[j + 3];
        }
        O[base] = (o0 + o1) + (o2 + o3);
        __syncthreads();
    }
}

// ---------- launch ----------
extern "C" void kernel_launch(void* const* d_in, const int* in_sizes, int n_in,
                              void* d_out, int out_size, void* d_ws, size_t ws_size,
                              hipStream_t stream) {
    const float* x     = (const float*)d_in[0];
    const float* Wq    = (const float*)d_in[1];
    const float* Wk    = (const float*)d_in[2];
    const float* Wv    = (const float*)d_in[3];
    const float* Wbeta = (const float*)d_in[4];
    const float* bbeta = (const float*)d_in[5];
    const float* Wout  = (const float*)d_in[6];
    float* out = (float*)d_out;

    const size_t projElems = (size_t)MROWS * DM;
    const size_t betaBytes = (size_t)MROWS * NH * 4;
    const size_t f32Bytes  = projElems * 4;
    const size_t bf16Bytes = projElems * 2;
    const size_t need_f32  = 3 * f32Bytes + betaBytes + f32Bytes;

    char* ws = (char*)d_ws;
    size_t off = 0;
    auto alloc = [&](size_t bytes) {
        char* p = ws + off;
        off += (bytes + 255) & ~(size_t)255;
        return (void*)p;
    };

    const dim3 gemmGrid(DM / BN, MROWS / BM);
    const dim3 gemmBlock(256);

    if (ws_size >= need_f32) {
        float* Qf = (float*)alloc(f32Bytes);
        float* Kf = (float*)alloc(f32Bytes);
        float* Vf = (float*)alloc(f32Bytes);
        float* betaf = (float*)alloc(betaBytes);
        float* Of = (float*)alloc(f32Bytes);

        gemm_kernel<float, float><<<gemmGrid, gemmBlock, 0, stream>>>(x, Wq, Qf, MROWS, DM, DM);
        gemm_kernel<float, float><<<gemmGrid, gemmBlock, 0, stream>>>(x, Wk, Kf, MROWS, DM, DM);
        gemm_kernel<float, float><<<gemmGrid, gemmBlock, 0, stream>>>(x, Wv, Vf, MROWS, DM, DM);
        beta_kernel<<<dim3(MROWS / 16), dim3(256), 0, stream>>>(x, Wbeta, bbeta, betaf);
        scan_chunked<<<dim3(BATCH * NH), dim3(256), 0, stream>>>(Qf, Kf, Vf, betaf, Of);
        gemm_kernel<float, float><<<gemmGrid, gemmBlock, 0, stream>>>(Of, Wout, out, MROWS, DM, DM);
    } else {
        __hip_bfloat16* Qh = (__hip_bfloat16*)alloc(bf16Bytes);
        __hip_bfloat16* Kh = (__hip_bfloat16*)alloc(bf16Bytes);
        __hip_bfloat16* Vh = (__hip_bfloat16*)alloc(bf16Bytes);
        float* betaf = (float*)alloc(betaBytes);
        float* Of = (float*)alloc(f32Bytes);

        gemm_kernel<float, __hip_bfloat16><<<gemmGrid, gemmBlock, 0, stream>>>(x, Wq, Qh, MROWS, DM, DM);
        gemm_kernel<float, __hip_bfloat16><<<gemmGrid, gemmBlock, 0, stream>>>(x, Wk, Kh, MROWS, DM, DM);
        gemm_kernel<float, __hip_bfloat16><<<gemmGrid, gemmBlock, 0, stream>>>(x, Wv, Vh, MROWS, DM, DM);
        beta_kernel<<<dim3(MROWS / 16), dim3(256), 0, stream>>>(x, Wbeta, bbeta, betaf);
        scan_kernel<__hip_bfloat16><<<dim3(BATCH * NH), dim3(64), 0, stream>>>(Qh, Kh, Vh, betaf, Of);
        gemm_kernel<float, float><<<gemmGrid, gemmBlock, 0, stream>>>(Of, Wout, out, MROWS, DM, DM);
    }
}

// Round 3
// 2358.236 us; speedup vs baseline: 2.0941x; 2.0941x over previous
//
#include <hip/hip_runtime.h>
#include <hip/hip_bf16.h>

// Problem constants (fixed by the reference)
#define BATCH 4
#define TSEQ 2048
#define DM 1024
#define NH 16
#define DH 64
#define MROWS (BATCH * TSEQ)  // 8192
#define CHUNK 64
#define LP 65    // pad for scalar-read LDS tiles: bank=(row+col)%32
#define RP 132   // RHS pad (rows stay 16B-aligned: 132*4=528)

// ---------- type helpers ----------
__device__ __forceinline__ float ldf(const float* p) { return *p; }
__device__ __forceinline__ float ldf(const __hip_bfloat16* p) { return __bfloat162float(*p); }
__device__ __forceinline__ void stf(float* p, float v) { *p = v; }
__device__ __forceinline__ void stf(__hip_bfloat16* p, float v) { *p = __float2bfloat16(v); }

// ---------- generic fp32-compute tiled GEMM: C(MxN) = A(MxK) @ B(KxN) ----------
#define BM 64
#define BN 64
#define BK 16

template <typename TA, typename TC>
__global__ __launch_bounds__(256) void gemm_kernel(const TA* __restrict__ A,
                                                   const float* __restrict__ B,
                                                   TC* __restrict__ C,
                                                   int M, int N, int K) {
    __shared__ float As[BK][BM + 1];
    __shared__ float Bs[BK][BN + 1];
    const int tid = threadIdx.x;
    const int tr = tid / 16;
    const int tc = tid % 16;
    const int rowBase = blockIdx.y * BM;
    const int colBase = blockIdx.x * BN;

    float acc[4][4];
#pragma unroll
    for (int m = 0; m < 4; ++m)
#pragma unroll
        for (int n = 0; n < 4; ++n) acc[m][n] = 0.f;

    for (int k0 = 0; k0 < K; k0 += BK) {
#pragma unroll
        for (int i = tid; i < BM * BK; i += 256) {
            int r = i / BK, c = i % BK;
            As[c][r] = ldf(&A[(size_t)(rowBase + r) * K + k0 + c]);
        }
#pragma unroll
        for (int i = tid; i < BK * BN; i += 256) {
            int r = i / BN, c = i % BN;
            Bs[r][c] = B[(size_t)(k0 + r) * N + colBase + c];
        }
        __syncthreads();
#pragma unroll
        for (int kk = 0; kk < BK; ++kk) {
            float a[4], b[4];
#pragma unroll
            for (int m = 0; m < 4; ++m) a[m] = As[kk][tr * 4 + m];
#pragma unroll
            for (int n = 0; n < 4; ++n) b[n] = Bs[kk][tc * 4 + n];
#pragma unroll
            for (int m = 0; m < 4; ++m)
#pragma unroll
                for (int n = 0; n < 4; ++n) acc[m][n] += a[m] * b[n];
        }
        __syncthreads();
    }
#pragma unroll
    for (int m = 0; m < 4; ++m)
#pragma unroll
        for (int n = 0; n < 4; ++n)
            stf(&C[(size_t)(rowBase + tr * 4 + m) * N + colBase + tc * 4 + n], acc[m][n]);
}

// ---------- beta = sigmoid(x @ Wbeta + b_beta) ----------
__global__ __launch_bounds__(256) void beta_kernel(const float* __restrict__ x,
                                                   const float* __restrict__ Wb,
                                                   const float* __restrict__ bb,
                                                   float* __restrict__ beta) {
    const int tid = threadIdx.x;
    const int h = tid % NH;
    const int rl = tid / NH;
    const int row = blockIdx.x * 16 + rl;
    const float* xr = x + (size_t)row * DM;
    float acc = 0.f;
#pragma unroll 8
    for (int k = 0; k < DM; ++k) acc += xr[k] * Wb[k * NH + h];
    acc += bb[h];
    beta[row * NH + h] = 1.f / (1.f + __expf(-acc));
}

// ---------- 4x4 outer-product FMA helper ----------
__device__ __forceinline__ void fma44(float (&acc)[4][4], const float* a, const float* b) {
#pragma unroll
    for (int m = 0; m < 4; ++m)
#pragma unroll
        for (int n = 0; n < 4; ++n) acc[m][n] += a[m] * b[n];
}

// ---------- Kernel A: chunk-local pre-pass (fully parallel over bh x chunk) ----------
// Per (bh, chunk):
//   Kn = rownorm(K)  (written back over K)
//   A[t][s] = beta_t * (kn_t . kn_s)   (strict lower used)
//   Gauss-solve (I+A) [u|w] = [beta*V | beta*Kn]
//   u -> over V, w -> w buffer
__global__ __launch_bounds__(256) void delta_prepass(float* __restrict__ K,
                                                     float* __restrict__ V,
                                                     const float* __restrict__ beta,
                                                     float* __restrict__ Wm) {
    const int chunk = blockIdx.x;
    const int bh = blockIdx.y;
    const int b = bh >> 4;
    const int h = bh & 15;
    const int tid = threadIdx.x;
    const int tr = tid >> 4;        // 0..15
    const int tc = tid & 15;        // 0..15
    const int lt = tid >> 2;        // 0..63 loader row
    const int j0 = (tid & 3) * 16;  // loader col quarter
    const int c0 = chunk * CHUNK;

    __shared__ __align__(16) float Kn[CHUNK][LP];
    __shared__ __align__(16) float Am[CHUNK][LP];
    __shared__ __align__(16) float RHS[CHUNK][RP];
    __shared__ float sbeta[CHUNK];

    const size_t gstride = NH * DH;  // 1024
    const size_t gbase = (size_t)b * TSEQ * gstride + (size_t)h * DH;
    float* kp = K + gbase + (size_t)(c0 + lt) * gstride + j0;
    float* vp = V + gbase + (size_t)(c0 + lt) * gstride + j0;

    // load K row-part, compute row L2 norm across the 4 threads of this row
    float4 k0 = ((const float4*)kp)[0];
    float4 k1 = ((const float4*)kp)[1];
    float4 k2 = ((const float4*)kp)[2];
    float4 k3 = ((const float4*)kp)[3];
    float ss = k0.x * k0.x + k0.y * k0.y + k0.z * k0.z + k0.w * k0.w +
               k1.x * k1.x + k1.y * k1.y + k1.z * k1.z + k1.w * k1.w +
               k2.x * k2.x + k2.y * k2.y + k2.z * k2.z + k2.w * k2.w +
               k3.x * k3.x + k3.y * k3.y + k3.z * k3.z + k3.w * k3.w;
    ss += __shfl_xor(ss, 1);
    ss += __shfl_xor(ss, 2);
    const float rn = 1.f / fmaxf(sqrtf(ss), 1e-12f);
    k0.x *= rn; k0.y *= rn; k0.z *= rn; k0.w *= rn;
    k1.x *= rn; k1.y *= rn; k1.z *= rn; k1.w *= rn;
    k2.x *= rn; k2.y *= rn; k2.z *= rn; k2.w *= rn;
    k3.x *= rn; k3.y *= rn; k3.z *= rn; k3.w *= rn;
    // write normalized K back to global and to LDS
    ((float4*)kp)[0] = k0; ((float4*)kp)[1] = k1;
    ((float4*)kp)[2] = k2; ((float4*)kp)[3] = k3;
    Kn[lt][j0 + 0] = k0.x;  Kn[lt][j0 + 1] = k0.y;  Kn[lt][j0 + 2] = k0.z;  Kn[lt][j0 + 3] = k0.w;
    Kn[lt][j0 + 4] = k1.x;  Kn[lt][j0 + 5] = k1.y;  Kn[lt][j0 + 6] = k1.z;  Kn[lt][j0 + 7] = k1.w;
    Kn[lt][j0 + 8] = k2.x;  Kn[lt][j0 + 9] = k2.y;  Kn[lt][j0 + 10] = k2.z; Kn[lt][j0 + 11] = k2.w;
    Kn[lt][j0 + 12] = k3.x; Kn[lt][j0 + 13] = k3.y; Kn[lt][j0 + 14] = k3.z; Kn[lt][j0 + 15] = k3.w;

    // V straight into registers
    float4 v0 = ((const float4*)vp)[0];
    float4 v1 = ((const float4*)vp)[1];
    float4 v2 = ((const float4*)vp)[2];
    float4 v3 = ((const float4*)vp)[3];

    if (tid < CHUNK)
        sbeta[tid] = beta[((size_t)(b * TSEQ + c0 + tid)) * NH + h];
    __syncthreads();

    // A = beta_t * Kn Kn^T
    {
        float acc[4][4];
#pragma unroll
        for (int m = 0; m < 4; ++m)
#pragma unroll
            for (int n = 0; n < 4; ++n) acc[m][n] = 0.f;
#pragma unroll 8
        for (int kk = 0; kk < DH; ++kk) {
            float a[4], bb2[4];
#pragma unroll
            for (int m = 0; m < 4; ++m) a[m] = Kn[tr * 4 + m][kk];
#pragma unroll
            for (int n = 0; n < 4; ++n) bb2[n] = Kn[tc * 4 + n][kk];
            fma44(acc, a, bb2);
        }
#pragma unroll
        for (int m = 0; m < 4; ++m) {
            const float bt = sbeta[tr * 4 + m];
#pragma unroll
            for (int n = 0; n < 4; ++n) Am[tr * 4 + m][tc * 4 + n] = bt * acc[m][n];
        }
    }
    // RHS = [beta*V | beta*Kn]
    {
        const float bl = sbeta[lt];
        *(float4*)&RHS[lt][j0 + 0]  = make_float4(bl * v0.x, bl * v0.y, bl * v0.z, bl * v0.w);
        *(float4*)&RHS[lt][j0 + 4]  = make_float4(bl * v1.x, bl * v1.y, bl * v1.z, bl * v1.w);
        *(float4*)&RHS[lt][j0 + 8]  = make_float4(bl * v2.x, bl * v2.y, bl * v2.z, bl * v2.w);
        *(float4*)&RHS[lt][j0 + 12] = make_float4(bl * v3.x, bl * v3.y, bl * v3.z, bl * v3.w);
        *(float4*)&RHS[lt][64 + j0 + 0]  = make_float4(bl * k0.x, bl * k0.y, bl * k0.z, bl * k0.w);
        *(float4*)&RHS[lt][64 + j0 + 4]  = make_float4(bl * k1.x, bl * k1.y, bl * k1.z, bl * k1.w);
        *(float4*)&RHS[lt][64 + j0 + 8]  = make_float4(bl * k2.x, bl * k2.y, bl * k2.z, bl * k2.w);
        *(float4*)&RHS[lt][64 + j0 + 12] = make_float4(bl * k3.x, bl * k3.y, bl * k3.z, bl * k3.w);
    }
    __syncthreads();

    // Gauss forward elimination: after step t, row t+1 is final.
    const int grow = tid >> 2;            // 0..63
    const int gc = (tid & 3) * 32;        // col quarter (32 wide, of 128)
    for (int t = 0; t < CHUNK - 1; ++t) {
        if (grow > t) {
            const float art = Am[grow][t];
#pragma unroll
            for (int c = 0; c < 32; c += 4) {
                float4 rt = *(const float4*)&RHS[t][gc + c];
                float4 rr = *(float4*)&RHS[grow][gc + c];
                rr.x -= art * rt.x; rr.y -= art * rt.y;
                rr.z -= art * rt.z; rr.w -= art * rt.w;
                *(float4*)&RHS[grow][gc + c] = rr;
            }
        }
        __syncthreads();
    }

    // write u (over V) and w
    float* wp = Wm + gbase + (size_t)(c0 + lt) * gstride + j0;
#pragma unroll
    for (int q = 0; q < 4; ++q) {
        ((float4*)vp)[q] = *(const float4*)&RHS[lt][j0 + 4 * q];
        ((float4*)wp)[q] = *(const float4*)&RHS[lt][64 + j0 + 4 * q];
    }
}

// ---------- Kernel B: thin sequential pass over chunks (dense 64^3 matmuls only) ----------
// Per chunk: U = u_pre - w S^T ; SS = tril(Q Kn^T, incl) ; O = Q S^T + SS U ; S += U^T Kn
// O written in-place over Q.
__global__ __launch_bounds__(256) void scan_seq(float* __restrict__ Q,
                                                const float* __restrict__ Kg,
                                                const float* __restrict__ Ug,
                                                const float* __restrict__ Wg) {
    const int bh = blockIdx.x;
    const int b = bh >> 4;
    const int h = bh & 15;
    const int tid = threadIdx.x;
    const int tr = tid >> 4;
    const int tc = tid & 15;
    const int lt = tid >> 2;
    const int j0 = (tid & 3) * 16;

    __shared__ float Ssm[DH][LP];    // S[i][j]
    __shared__ float Qs[CHUNK][LP];
    __shared__ float Ks[CHUNK][LP];
    __shared__ float Ws[CHUNK][LP];
    __shared__ float Us[CHUNK][LP];
    __shared__ float SSs[CHUNK][LP];

    for (int idx = tid; idx < DH * DH; idx += 256) Ssm[idx >> 6][idx & 63] = 0.f;

    const size_t gstride = NH * DH;
    const size_t gbase = (size_t)b * TSEQ * gstride + (size_t)h * DH;

    for (int c0 = 0; c0 < TSEQ; c0 += CHUNK) {
        // stage Q, Kn, w chunks into LDS
        {
            const float* qp = Q + gbase + (size_t)(c0 + lt) * gstride + j0;
            const float* kp = Kg + gbase + (size_t)(c0 + lt) * gstride + j0;
            const float* wp = Wg + gbase + (size_t)(c0 + lt) * gstride + j0;
#pragma unroll
            for (int q = 0; q < 4; ++q) {
                float4 a = ((const float4*)qp)[q];
                float4 bb2 = ((const float4*)kp)[q];
                float4 cc = ((const float4*)wp)[q];
                Qs[lt][j0 + 4 * q + 0] = a.x; Qs[lt][j0 + 4 * q + 1] = a.y;
                Qs[lt][j0 + 4 * q + 2] = a.z; Qs[lt][j0 + 4 * q + 3] = a.w;
                Ks[lt][j0 + 4 * q + 0] = bb2.x; Ks[lt][j0 + 4 * q + 1] = bb2.y;
                Ks[lt][j0 + 4 * q + 2] = bb2.z; Ks[lt][j0 + 4 * q + 3] = bb2.w;
                Ws[lt][j0 + 4 * q + 0] = cc.x; Ws[lt][j0 + 4 * q + 1] = cc.y;
                Ws[lt][j0 + 4 * q + 2] = cc.z; Ws[lt][j0 + 4 * q + 3] = cc.w;
            }
        }
        __syncthreads();

        // phase 1: accU = w S^T ; accO = Q S^T ; accSS = Q Kn^T
        float accU[4][4], accO[4][4], accSS[4][4];
#pragma unroll
        for (int m = 0; m < 4; ++m)
#pragma unroll
            for (int n = 0; n < 4; ++n) { accU[m][n] = 0.f; accO[m][n] = 0.f; accSS[m][n] = 0.f; }
#pragma unroll 8
        for (int kk = 0; kk < DH; ++kk) {
            float aW[4], aQ[4], bS[4], bK[4];
#pragma unroll
            for (int m = 0; m < 4; ++m) { aW[m] = Ws[tr * 4 + m][kk]; aQ[m] = Qs[tr * 4 + m][kk]; }
#pragma unroll
            for (int n = 0; n < 4; ++n) { bS[n] = Ssm[tc * 4 + n][kk]; bK[n] = Ks[tc * 4 + n][kk]; }
            fma44(accU, aW, bS);
            fma44(accO, aQ, bS);
            fma44(accSS, aQ, bK);
        }
        // U = u_pre - accU ; SS masked
#pragma unroll
        for (int m = 0; m < 4; ++m) {
            const int r = tr * 4 + m;
            float4 u4 = *(const float4*)(Ug + gbase + (size_t)(c0 + r) * gstride + tc * 4);
            Us[r][tc * 4 + 0] = u4.x - accU[m][0];
            Us[r][tc * 4 + 1] = u4.y - accU[m][1];
            Us[r][tc * 4 + 2] = u4.z - accU[m][2];
            Us[r][tc * 4 + 3] = u4.w - accU[m][3];
#pragma unroll
            for (int n = 0; n < 4; ++n)
                SSs[r][tc * 4 + n] = (r >= tc * 4 + n) ? accSS[m][n] : 0.f;
        }
        __syncthreads();

        // phase 2: accO += SS U ; accS = U^T Kn
        float accS[4][4];
#pragma unroll
        for (int m = 0; m < 4; ++m)
#pragma unroll
            for (int n = 0; n < 4; ++n) accS[m][n] = 0.f;
#pragma unroll 8
        for (int kk = 0; kk < CHUNK; ++kk) {
            float aSS[4], aU[4], bU[4], bK[4];
#pragma unroll
            for (int m = 0; m < 4; ++m) { aSS[m] = SSs[tr * 4 + m][kk]; aU[m] = Us[kk][tr * 4 + m]; }
#pragma unroll
            for (int n = 0; n < 4; ++n) { bU[n] = Us[kk][tc * 4 + n]; bK[n] = Ks[kk][tc * 4 + n]; }
            fma44(accO, aSS, bU);
            fma44(accS, aU, bK);
        }
        // O over Q ; S += accS
#pragma unroll
        for (int m = 0; m < 4; ++m) {
            *(float4*)(Q + gbase + (size_t)(c0 + tr * 4 + m) * gstride + tc * 4) =
                make_float4(accO[m][0], accO[m][1], accO[m][2], accO[m][3]);
#pragma unroll
            for (int n = 0; n < 4; ++n) Ssm[tr * 4 + m][tc * 4 + n] += accS[m][n];
        }
        __syncthreads();
    }
}

// ---------- legacy sequential scan (bf16 fallback path only) ----------
template <typename TS>
__global__ __launch_bounds__(64) void scan_kernel(const TS* __restrict__ Q,
                                                  const TS* __restrict__ K,
                                                  const TS* __restrict__ V,
                                                  const float* __restrict__ beta,
                                                  float* __restrict__ O) {
    const int bh = blockIdx.x;
    const int b = bh >> 4;
    const int h = bh & 15;
    const int lane = threadIdx.x;

    float Wrow[64];
#pragma unroll
    for (int j = 0; j < 64; ++j) Wrow[j] = 0.f;

    __shared__ float sk[64];
    __shared__ float sq[64];

    size_t base = ((size_t)b * TSEQ) * (NH * DH) + h * DH + lane;
    int brow = b * TSEQ;

    for (int t = 0; t < TSEQ; ++t, base += NH * DH) {
        float k = ldf(&K[base]);
        float q = ldf(&Q[base]);
        float v = ldf(&V[base]);
        float be = beta[(size_t)(brow + t) * NH + h];

        float ss = k * k;
#pragma unroll
        for (int off = 32; off > 0; off >>= 1) ss += __shfl_xor(ss, off);
        k = k / fmaxf(sqrtf(ss), 1e-12f);

        sk[lane] = k;
        sq[lane] = q;
        __syncthreads();

        float p0 = 0.f, p1 = 0.f, p2 = 0.f, p3 = 0.f;
#pragma unroll
        for (int j = 0; j < 64; j += 4) {
            p0 += Wrow[j + 0] * sk[j + 0];
            p1 += Wrow[j + 1] * sk[j + 1];
            p2 += Wrow[j + 2] * sk[j + 2];
            p3 += Wrow[j + 3] * sk[j + 3];
        }
        const float bei = be * (v - ((p0 + p1) + (p2 + p3)));

        float o0 = 0.f, o1 = 0.f, o2 = 0.f, o3 = 0.f;
#pragma unroll
        for (int j = 0; j < 64; j += 4) {
            Wrow[j + 0] += bei * sk[j + 0]; o0 += Wrow[j + 0] * sq[j + 0];
            Wrow[j + 1] += bei * sk[j + 1]; o1 += Wrow[j + 1] * sq[j + 1];
            Wrow[j + 2] += bei * sk[j + 2]; o2 += Wrow[j + 2] * sq[j + 2];
            Wrow[j + 3] += bei * sk[j + 3]; o3 += Wrow[j + 3] * sq[j + 3];
        }
        O[base] = (o0 + o1) + (o2 + o3);
        __syncthreads();
    }
}

// ---------- launch ----------
extern "C" void kernel_launch(void* const* d_in, const int* in_sizes, int n_in,
                              void* d_out, int out_size, void* d_ws, size_t ws_size,
                              hipStream_t stream) {
    const float* x     = (const float*)d_in[0];
    const float* Wq    = (const float*)d_in[1];
    const float* Wk    = (const float*)d_in[2];
    const float* Wv    = (const float*)d_in[3];
    const float* Wbeta = (const float*)d_in[4];
    const float* bbeta = (const float*)d_in[5];
    const float* Wout  = (const float*)d_in[6];
    float* out = (float*)d_out;

    const size_t projElems = (size_t)MROWS * DM;
    const size_t betaBytes = (size_t)MROWS * NH * 4;
    const size_t f32Bytes  = projElems * 4;
    const size_t bf16Bytes = projElems * 2;
    const size_t need_f32  = 4 * f32Bytes + betaBytes;  // Q(->O), K(->Kn), V(->u), w, beta

    char* ws = (char*)d_ws;
    size_t off = 0;
    auto alloc = [&](size_t bytes) {
        char* p = ws + off;
        off += (bytes + 255) & ~(size_t)255;
        return (void*)p;
    };

    const dim3 gemmGrid(DM / BN, MROWS / BM);
    const dim3 gemmBlock(256);

    if (ws_size >= need_f32) {
        float* Qf = (float*)alloc(f32Bytes);    // becomes O in-place
        float* Kf = (float*)alloc(f32Bytes);    // becomes Kn in-place
        float* Vf = (float*)alloc(f32Bytes);    // becomes u_pre in-place
        float* Wmf = (float*)alloc(f32Bytes);   // w
        float* betaf = (float*)alloc(betaBytes);

        gemm_kernel<float, float><<<gemmGrid, gemmBlock, 0, stream>>>(x, Wq, Qf, MROWS, DM, DM);
        gemm_kernel<float, float><<<gemmGrid, gemmBlock, 0, stream>>>(x, Wk, Kf, MROWS, DM, DM);
        gemm_kernel<float, float><<<gemmGrid, gemmBlock, 0, stream>>>(x, Wv, Vf, MROWS, DM, DM);
        beta_kernel<<<dim3(MROWS / 16), dim3(256), 0, stream>>>(x, Wbeta, bbeta, betaf);
        delta_prepass<<<dim3(TSEQ / CHUNK, BATCH * NH), dim3(256), 0, stream>>>(Kf, Vf, betaf, Wmf);
        scan_seq<<<dim3(BATCH * NH), dim3(256), 0, stream>>>(Qf, Kf, Vf, Wmf);
        gemm_kernel<float, float><<<gemmGrid, gemmBlock, 0, stream>>>(Qf, Wout, out, MROWS, DM, DM);
    } else {
        __hip_bfloat16* Qh = (__hip_bfloat16*)alloc(bf16Bytes);
        __hip_bfloat16* Kh = (__hip_bfloat16*)alloc(bf16Bytes);
        __hip_bfloat16* Vh = (__hip_bfloat16*)alloc(bf16Bytes);
        float* betaf = (float*)alloc(betaBytes);
        float* Of = (float*)alloc(f32Bytes);

        gemm_kernel<float, __hip_bfloat16><<<gemmGrid, gemmBlock, 0, stream>>>(x, Wq, Qh, MROWS, DM, DM);
        gemm_kernel<float, __hip_bfloat16><<<gemmGrid, gemmBlock, 0, stream>>>(x, Wk, Kh, MROWS, DM, DM);
        gemm_kernel<float, __hip_bfloat16><<<gemmGrid, gemmBlock, 0, stream>>>(x, Wv, Vh, MROWS, DM, DM);
        beta_kernel<<<dim3(MROWS / 16), dim3(256), 0, stream>>>(x, Wbeta, bbeta, betaf);
        scan_kernel<__hip_bfloat16><<<dim3(BATCH * NH), dim3(64), 0, stream>>>(Qh, Kh, Vh, betaf, Of);
        gemm_kernel<float, float><<<gemmGrid, gemmBlock, 0, stream>>>(Of, Wout, out, MROWS, DM, DM);
    }
}

// Round 4
// 955.482 us; speedup vs baseline: 5.1684x; 2.4681x over previous
//
#include <hip/hip_runtime.h>
#include <hip/hip_bf16.h>

// Problem constants (fixed by the reference)
#define BATCH 4
#define TSEQ 2048
#define DM 1024
#define NH 16
#define DH 64
#define MROWS (BATCH * TSEQ)  // 8192
#define CHUNK 64
#define LP 65    // pad for scalar-read LDS tiles
#define RP 132   // RHS pad

typedef __attribute__((ext_vector_type(8))) short bf16x8;
typedef __attribute__((ext_vector_type(4))) float f32x4;

#define GLOAD16(g, l)                                                        \
    __builtin_amdgcn_global_load_lds(                                        \
        (const __attribute__((address_space(1))) void*)(g),                  \
        (__attribute__((address_space(3))) void*)(l), 16, 0, 0)

// ---------- type helpers ----------
__device__ __forceinline__ float ldf(const float* p) { return *p; }
__device__ __forceinline__ float ldf(const __hip_bfloat16* p) { return __bfloat162float(*p); }
__device__ __forceinline__ void stf(float* p, float v) { *p = v; }
__device__ __forceinline__ void stf(__hip_bfloat16* p, float v) { *p = __float2bfloat16(v); }

// ================= bf16 MFMA GEMM: C[M][N] = A[M][K] @ B[K][N] =================
// A given bf16 row-major (M x K); B given TRANSPOSED bf16 (BT[N][K] row-major).
// 128x128 tile, BK=32, 256 threads = 4 waves (2x2), each wave a 64x64 subtile.
__global__ __launch_bounds__(256) void gemm_mfma(const __hip_bfloat16* __restrict__ Ah,
                                                 const __hip_bfloat16* __restrict__ BT,
                                                 float* __restrict__ C,
                                                 int M, int N, int K) {
    __shared__ __align__(16) __hip_bfloat16 As[128 * 32];
    __shared__ __align__(16) __hip_bfloat16 Bs[128 * 32];
    const int tid = threadIdx.x;
    const int wave = tid >> 6;
    const int lane = tid & 63;
    const int wr = wave >> 1;  // 0..1
    const int wc = wave & 1;   // 0..1
    const int rowBase = blockIdx.y * 128;
    const int colBase = blockIdx.x * 128;

    f32x4 acc[4][4] = {};

    // Staging geometry: LDS tile row = 32 bf16 = 64 B = 4 slots of 16 B.
    // LDS(row, sl) holds global k-slot sg = (sl - (row>>1)) & 3  (inverse swizzle
    // on the SOURCE; LDS write itself is linear lane*16 per global_load_lds).
    const int r0 = wave * 16 + (lane >> 2);  // rows 0..63   (load 0)
    const int r1 = r0 + 64;                  // rows 64..127 (load 1)
    const int sl = lane & 3;
    const int sg0 = (sl - (r0 >> 1)) & 3;
    const int sg1 = (sl - (r1 >> 1)) & 3;
    const size_t Kz = (size_t)K;

    // compute-side LDS byte offsets (swizzled): row*64 + ((kslot + row>>1)&3)*16
    int offA[4], offB[4];
#pragma unroll
    for (int i = 0; i < 4; ++i) {
        const int rowa = wr * 64 + i * 16 + (lane & 15);
        const int rowb = wc * 64 + i * 16 + (lane & 15);
        offA[i] = rowa * 64 + ((((lane >> 4) + (rowa >> 1)) & 3) * 16);
        offB[i] = rowb * 64 + ((((lane >> 4) + (rowb >> 1)) & 3) * 16);
    }

    for (int k0 = 0; k0 < K; k0 += 32) {
        const __hip_bfloat16* ga0 = Ah + ((size_t)(rowBase + r0) * Kz + k0 + sg0 * 8);
        const __hip_bfloat16* ga1 = Ah + ((size_t)(rowBase + r1) * Kz + k0 + sg1 * 8);
        const __hip_bfloat16* gb0 = BT + ((size_t)(colBase + r0) * Kz + k0 + sg0 * 8);
        const __hip_bfloat16* gb1 = BT + ((size_t)(colBase + r1) * Kz + k0 + sg1 * 8);
        char* lA = (char*)As + wave * 1024;
        char* lB = (char*)Bs + wave * 1024;
        GLOAD16(ga0, lA);
        GLOAD16(ga1, lA + 4096);
        GLOAD16(gb0, lB);
        GLOAD16(gb1, lB + 4096);
        __syncthreads();  // drains vmcnt (incl. global_load_lds) + barrier

        bf16x8 af[4], bfr[4];
#pragma unroll
        for (int i = 0; i < 4; ++i) af[i] = *(const bf16x8*)((const char*)As + offA[i]);
#pragma unroll
        for (int i = 0; i < 4; ++i) bfr[i] = *(const bf16x8*)((const char*)Bs + offB[i]);
#pragma unroll
        for (int mi = 0; mi < 4; ++mi)
#pragma unroll
            for (int ni = 0; ni < 4; ++ni)
                acc[mi][ni] =
                    __builtin_amdgcn_mfma_f32_16x16x32_bf16(af[mi], bfr[ni], acc[mi][ni], 0, 0, 0);
        __syncthreads();  // protect LDS reuse
    }

    // Epilogue: D layout col = lane&15, row = (lane>>4)*4 + reg  [m89-verified]
#pragma unroll
    for (int mi = 0; mi < 4; ++mi)
#pragma unroll
        for (int ni = 0; ni < 4; ++ni) {
            const int col = colBase + wc * 64 + ni * 16 + (lane & 15);
#pragma unroll
            for (int r = 0; r < 4; ++r) {
                const int row = rowBase + wr * 64 + mi * 16 + (lane >> 4) * 4 + r;
                C[(size_t)row * N + col] = acc[mi][ni][r];
            }
        }
}

// ---------- conversions ----------
// fp32 -> bf16, 8 elems/thread
__global__ __launch_bounds__(256) void conv_bf16(const float* __restrict__ in,
                                                 __hip_bfloat16* __restrict__ out, int n8) {
    const int i = blockIdx.x * 256 + threadIdx.x;
    if (i >= n8) return;
    const float4* p = (const float4*)in + (size_t)i * 2;
    float4 a = p[0], b = p[1];
    __hip_bfloat16 t[8] = {__float2bfloat16(a.x), __float2bfloat16(a.y),
                           __float2bfloat16(a.z), __float2bfloat16(a.w),
                           __float2bfloat16(b.x), __float2bfloat16(b.y),
                           __float2bfloat16(b.z), __float2bfloat16(b.w)};
    *(uint4*)(out + (size_t)i * 8) = *(const uint4*)t;
}

// W[K=1024][N=1024] fp32 -> WT[N][K] bf16 (transpose), 64x64 tiles
__global__ __launch_bounds__(256) void convT_bf16(const float* __restrict__ W,
                                                  __hip_bfloat16* __restrict__ WT) {
    __shared__ __hip_bfloat16 tile[64][65];
    const int tid = threadIdx.x;
    const int c = tid & 63;
    const int r4 = tid >> 6;  // 0..3
    const int kb = blockIdx.y * 64;
    const int nb = blockIdx.x * 64;
#pragma unroll
    for (int i = 0; i < 16; ++i) {
        const int r = r4 + i * 4;
        tile[r][c] = __float2bfloat16(W[(size_t)(kb + r) * DM + nb + c]);
    }
    __syncthreads();
#pragma unroll
    for (int i = 0; i < 16; ++i) {
        const int r = r4 + i * 4;  // output row block (n)
        WT[(size_t)(nb + r) * DM + kb + c] = tile[c][r];
    }
}

// ---------- beta = sigmoid(x @ Wbeta + b_beta) ----------
__global__ __launch_bounds__(256) void beta_kernel(const float* __restrict__ x,
                                                   const float* __restrict__ Wb,
                                                   const float* __restrict__ bb,
                                                   float* __restrict__ beta) {
    const int tid = threadIdx.x;
    const int h = tid % NH;
    const int rl = tid / NH;
    const int row = blockIdx.x * 16 + rl;
    const float* xr = x + (size_t)row * DM;
    float acc = 0.f;
#pragma unroll 8
    for (int k = 0; k < DM; ++k) acc += xr[k] * Wb[k * NH + h];
    acc += bb[h];
    beta[row * NH + h] = 1.f / (1.f + __expf(-acc));
}

// ---------- 4x4 outer-product FMA helper ----------
__device__ __forceinline__ void fma44(float (&acc)[4][4], const float* a, const float* b) {
#pragma unroll
    for (int m = 0; m < 4; ++m)
#pragma unroll
        for (int n = 0; n < 4; ++n) acc[m][n] += a[m] * b[n];
}

// ---------- Kernel A: chunk-local pre-pass (parallel over bh x chunk) ----------
__global__ __launch_bounds__(256) void delta_prepass(float* __restrict__ K,
                                                     float* __restrict__ V,
                                                     const float* __restrict__ beta,
                                                     float* __restrict__ Wm) {
    const int chunk = blockIdx.x;
    const int bh = blockIdx.y;
    const int b = bh >> 4;
    const int h = bh & 15;
    const int tid = threadIdx.x;
    const int tr = tid >> 4;
    const int tc = tid & 15;
    const int lt = tid >> 2;
    const int j0 = (tid & 3) * 16;
    const int c0 = chunk * CHUNK;

    __shared__ __align__(16) float Kn[CHUNK][LP];
    __shared__ __align__(16) float Am[CHUNK][LP];
    __shared__ __align__(16) float RHS[CHUNK][RP];
    __shared__ float sbeta[CHUNK];

    const size_t gstride = NH * DH;
    const size_t gbase = (size_t)b * TSEQ * gstride + (size_t)h * DH;
    float* kp = K + gbase + (size_t)(c0 + lt) * gstride + j0;
    float* vp = V + gbase + (size_t)(c0 + lt) * gstride + j0;

    float4 k0 = ((const float4*)kp)[0];
    float4 k1 = ((const float4*)kp)[1];
    float4 k2 = ((const float4*)kp)[2];
    float4 k3 = ((const float4*)kp)[3];
    float ss = k0.x * k0.x + k0.y * k0.y + k0.z * k0.z + k0.w * k0.w +
               k1.x * k1.x + k1.y * k1.y + k1.z * k1.z + k1.w * k1.w +
               k2.x * k2.x + k2.y * k2.y + k2.z * k2.z + k2.w * k2.w +
               k3.x * k3.x + k3.y * k3.y + k3.z * k3.z + k3.w * k3.w;
    ss += __shfl_xor(ss, 1);
    ss += __shfl_xor(ss, 2);
    const float rn = 1.f / fmaxf(sqrtf(ss), 1e-12f);
    k0.x *= rn; k0.y *= rn; k0.z *= rn; k0.w *= rn;
    k1.x *= rn; k1.y *= rn; k1.z *= rn; k1.w *= rn;
    k2.x *= rn; k2.y *= rn; k2.z *= rn; k2.w *= rn;
    k3.x *= rn; k3.y *= rn; k3.z *= rn; k3.w *= rn;
    ((float4*)kp)[0] = k0; ((float4*)kp)[1] = k1;
    ((float4*)kp)[2] = k2; ((float4*)kp)[3] = k3;
    Kn[lt][j0 + 0] = k0.x;  Kn[lt][j0 + 1] = k0.y;  Kn[lt][j0 + 2] = k0.z;  Kn[lt][j0 + 3] = k0.w;
    Kn[lt][j0 + 4] = k1.x;  Kn[lt][j0 + 5] = k1.y;  Kn[lt][j0 + 6] = k1.z;  Kn[lt][j0 + 7] = k1.w;
    Kn[lt][j0 + 8] = k2.x;  Kn[lt][j0 + 9] = k2.y;  Kn[lt][j0 + 10] = k2.z; Kn[lt][j0 + 11] = k2.w;
    Kn[lt][j0 + 12] = k3.x; Kn[lt][j0 + 13] = k3.y; Kn[lt][j0 + 14] = k3.z; Kn[lt][j0 + 15] = k3.w;

    float4 v0 = ((const float4*)vp)[0];
    float4 v1 = ((const float4*)vp)[1];
    float4 v2 = ((const float4*)vp)[2];
    float4 v3 = ((const float4*)vp)[3];

    if (tid < CHUNK)
        sbeta[tid] = beta[((size_t)(b * TSEQ + c0 + tid)) * NH + h];
    __syncthreads();

    {
        float acc[4][4];
#pragma unroll
        for (int m = 0; m < 4; ++m)
#pragma unroll
            for (int n = 0; n < 4; ++n) acc[m][n] = 0.f;
#pragma unroll 8
        for (int kk = 0; kk < DH; ++kk) {
            float a[4], bb2[4];
#pragma unroll
            for (int m = 0; m < 4; ++m) a[m] = Kn[tr * 4 + m][kk];
#pragma unroll
            for (int n = 0; n < 4; ++n) bb2[n] = Kn[tc * 4 + n][kk];
            fma44(acc, a, bb2);
        }
#pragma unroll
        for (int m = 0; m < 4; ++m) {
            const float bt = sbeta[tr * 4 + m];
#pragma unroll
            for (int n = 0; n < 4; ++n) Am[tr * 4 + m][tc * 4 + n] = bt * acc[m][n];
        }
    }
    {
        const float bl = sbeta[lt];
        *(float4*)&RHS[lt][j0 + 0]  = make_float4(bl * v0.x, bl * v0.y, bl * v0.z, bl * v0.w);
        *(float4*)&RHS[lt][j0 + 4]  = make_float4(bl * v1.x, bl * v1.y, bl * v1.z, bl * v1.w);
        *(float4*)&RHS[lt][j0 + 8]  = make_float4(bl * v2.x, bl * v2.y, bl * v2.z, bl * v2.w);
        *(float4*)&RHS[lt][j0 + 12] = make_float4(bl * v3.x, bl * v3.y, bl * v3.z, bl * v3.w);
        *(float4*)&RHS[lt][64 + j0 + 0]  = make_float4(bl * k0.x, bl * k0.y, bl * k0.z, bl * k0.w);
        *(float4*)&RHS[lt][64 + j0 + 4]  = make_float4(bl * k1.x, bl * k1.y, bl * k1.z, bl * k1.w);
        *(float4*)&RHS[lt][64 + j0 + 8]  = make_float4(bl * k2.x, bl * k2.y, bl * k2.z, bl * k2.w);
        *(float4*)&RHS[lt][64 + j0 + 12] = make_float4(bl * k3.x, bl * k3.y, bl * k3.z, bl * k3.w);
    }
    __syncthreads();

    const int grow = tid >> 2;
    const int gc = (tid & 3) * 32;
    for (int t = 0; t < CHUNK - 1; ++t) {
        if (grow > t) {
            const float art = Am[grow][t];
#pragma unroll
            for (int c = 0; c < 32; c += 4) {
                float4 rt = *(const float4*)&RHS[t][gc + c];
                float4 rr = *(float4*)&RHS[grow][gc + c];
                rr.x -= art * rt.x; rr.y -= art * rt.y;
                rr.z -= art * rt.z; rr.w -= art * rt.w;
                *(float4*)&RHS[grow][gc + c] = rr;
            }
        }
        __syncthreads();
    }

    float* wp = Wm + gbase + (size_t)(c0 + lt) * gstride + j0;
#pragma unroll
    for (int q = 0; q < 4; ++q) {
        ((float4*)vp)[q] = *(const float4*)&RHS[lt][j0 + 4 * q];
        ((float4*)wp)[q] = *(const float4*)&RHS[lt][64 + j0 + 4 * q];
    }
}

// ---------- Kernel B: thin sequential pass over chunks ----------
__global__ __launch_bounds__(256) void scan_seq(float* __restrict__ Q,
                                                const float* __restrict__ Kg,
                                                const float* __restrict__ Ug,
                                                const float* __restrict__ Wg) {
    const int bh = blockIdx.x;
    const int b = bh >> 4;
    const int h = bh & 15;
    const int tid = threadIdx.x;
    const int tr = tid >> 4;
    const int tc = tid & 15;
    const int lt = tid >> 2;
    const int j0 = (tid & 3) * 16;

    __shared__ float Ssm[DH][LP];
    __shared__ float Qs[CHUNK][LP];
    __shared__ float Ks[CHUNK][LP];
    __shared__ float Ws[CHUNK][LP];
    __shared__ float Us[CHUNK][LP];
    __shared__ float SSs[CHUNK][LP];

    for (int idx = tid; idx < DH * DH; idx += 256) Ssm[idx >> 6][idx & 63] = 0.f;

    const size_t gstride = NH * DH;
    const size_t gbase = (size_t)b * TSEQ * gstride + (size_t)h * DH;

    for (int c0 = 0; c0 < TSEQ; c0 += CHUNK) {
        {
            const float* qp = Q + gbase + (size_t)(c0 + lt) * gstride + j0;
            const float* kp = Kg + gbase + (size_t)(c0 + lt) * gstride + j0;
            const float* wp = Wg + gbase + (size_t)(c0 + lt) * gstride + j0;
#pragma unroll
            for (int q = 0; q < 4; ++q) {
                float4 a = ((const float4*)qp)[q];
                float4 bb2 = ((const float4*)kp)[q];
                float4 cc = ((const float4*)wp)[q];
                Qs[lt][j0 + 4 * q + 0] = a.x; Qs[lt][j0 + 4 * q + 1] = a.y;
                Qs[lt][j0 + 4 * q + 2] = a.z; Qs[lt][j0 + 4 * q + 3] = a.w;
                Ks[lt][j0 + 4 * q + 0] = bb2.x; Ks[lt][j0 + 4 * q + 1] = bb2.y;
                Ks[lt][j0 + 4 * q + 2] = bb2.z; Ks[lt][j0 + 4 * q + 3] = bb2.w;
                Ws[lt][j0 + 4 * q + 0] = cc.x; Ws[lt][j0 + 4 * q + 1] = cc.y;
                Ws[lt][j0 + 4 * q + 2] = cc.z; Ws[lt][j0 + 4 * q + 3] = cc.w;
            }
        }
        __syncthreads();

        float accU[4][4], accO[4][4], accSS[4][4];
#pragma unroll
        for (int m = 0; m < 4; ++m)
#pragma unroll
            for (int n = 0; n < 4; ++n) { accU[m][n] = 0.f; accO[m][n] = 0.f; accSS[m][n] = 0.f; }
#pragma unroll 8
        for (int kk = 0; kk < DH; ++kk) {
            float aW[4], aQ[4], bS[4], bK[4];
#pragma unroll
            for (int m = 0; m < 4; ++m) { aW[m] = Ws[tr * 4 + m][kk]; aQ[m] = Qs[tr * 4 + m][kk]; }
#pragma unroll
            for (int n = 0; n < 4; ++n) { bS[n] = Ssm[tc * 4 + n][kk]; bK[n] = Ks[tc * 4 + n][kk]; }
            fma44(accU, aW, bS);
            fma44(accO, aQ, bS);
            fma44(accSS, aQ, bK);
        }
#pragma unroll
        for (int m = 0; m < 4; ++m) {
            const int r = tr * 4 + m;
            float4 u4 = *(const float4*)(Ug + gbase + (size_t)(c0 + r) * gstride + tc * 4);
            Us[r][tc * 4 + 0] = u4.x - accU[m][0];
            Us[r][tc * 4 + 1] = u4.y - accU[m][1];
            Us[r][tc * 4 + 2] = u4.z - accU[m][2];
            Us[r][tc * 4 + 3] = u4.w - accU[m][3];
#pragma unroll
            for (int n = 0; n < 4; ++n)
                SSs[r][tc * 4 + n] = (r >= tc * 4 + n) ? accSS[m][n] : 0.f;
        }
        __syncthreads();

        float accS[4][4];
#pragma unroll
        for (int m = 0; m < 4; ++m)
#pragma unroll
            for (int n = 0; n < 4; ++n) accS[m][n] = 0.f;
#pragma unroll 8
        for (int kk = 0; kk < CHUNK; ++kk) {
            float aSS[4], aU[4], bU[4], bK[4];
#pragma unroll
            for (int m = 0; m < 4; ++m) { aSS[m] = SSs[tr * 4 + m][kk]; aU[m] = Us[kk][tr * 4 + m]; }
#pragma unroll
            for (int n = 0; n < 4; ++n) { bU[n] = Us[kk][tc * 4 + n]; bK[n] = Ks[kk][tc * 4 + n]; }
            fma44(accO, aSS, bU);
            fma44(accS, aU, bK);
        }
#pragma unroll
        for (int m = 0; m < 4; ++m) {
            *(float4*)(Q + gbase + (size_t)(c0 + tr * 4 + m) * gstride + tc * 4) =
                make_float4(accO[m][0], accO[m][1], accO[m][2], accO[m][3]);
#pragma unroll
            for (int n = 0; n < 4; ++n) Ssm[tr * 4 + m][tc * 4 + n] += accS[m][n];
        }
        __syncthreads();
    }
}

// ---------- legacy fp32 tiled GEMM + sequential scan (fallback path only) ----------
#define BM 64
#define BN 64
#define BK 16

template <typename TA, typename TC>
__global__ __launch_bounds__(256) void gemm_kernel(const TA* __restrict__ A,
                                                   const float* __restrict__ B,
                                                   TC* __restrict__ C,
                                                   int M, int N, int K) {
    __shared__ float As[BK][BM + 1];
    __shared__ float Bs[BK][BN + 1];
    const int tid = threadIdx.x;
    const int tr = tid / 16;
    const int tc = tid % 16;
    const int rowBase = blockIdx.y * BM;
    const int colBase = blockIdx.x * BN;

    float acc[4][4];
#pragma unroll
    for (int m = 0; m < 4; ++m)
#pragma unroll
        for (int n = 0; n < 4; ++n) acc[m][n] = 0.f;

    for (int k0 = 0; k0 < K; k0 += BK) {
#pragma unroll
        for (int i = tid; i < BM * BK; i += 256) {
            int r = i / BK, c = i % BK;
            As[c][r] = ldf(&A[(size_t)(rowBase + r) * K + k0 + c]);
        }
#pragma unroll
        for (int i = tid; i < BK * BN; i += 256) {
            int r = i / BN, c = i % BN;
            Bs[r][c] = B[(size_t)(k0 + r) * N + colBase + c];
        }
        __syncthreads();
#pragma unroll
        for (int kk = 0; kk < BK; ++kk) {
            float a[4], b[4];
#pragma unroll
            for (int m = 0; m < 4; ++m) a[m] = As[kk][tr * 4 + m];
#pragma unroll
            for (int n = 0; n < 4; ++n) b[n] = Bs[kk][tc * 4 + n];
#pragma unroll
            for (int m = 0; m < 4; ++m)
#pragma unroll
                for (int n = 0; n < 4; ++n) acc[m][n] += a[m] * b[n];
        }
        __syncthreads();
    }
#pragma unroll
    for (int m = 0; m < 4; ++m)
#pragma unroll
        for (int n = 0; n < 4; ++n)
            stf(&C[(size_t)(rowBase + tr * 4 + m) * N + colBase + tc * 4 + n], acc[m][n]);
}

template <typename TS>
__global__ __launch_bounds__(64) void scan_kernel(const TS* __restrict__ Q,
                                                  const TS* __restrict__ K,
                                                  const TS* __restrict__ V,
                                                  const float* __restrict__ beta,
                                                  float* __restrict__ O) {
    const int bh = blockIdx.x;
    const int b = bh >> 4;
    const int h = bh & 15;
    const int lane = threadIdx.x;

    float Wrow[64];
#pragma unroll
    for (int j = 0; j < 64; ++j) Wrow[j] = 0.f;

    __shared__ float sk[64];
    __shared__ float sq[64];

    size_t base = ((size_t)b * TSEQ) * (NH * DH) + h * DH + lane;
    int brow = b * TSEQ;

    for (int t = 0; t < TSEQ; ++t, base += NH * DH) {
        float k = ldf(&K[base]);
        float q = ldf(&Q[base]);
        float v = ldf(&V[base]);
        float be = beta[(size_t)(brow + t) * NH + h];

        float ss = k * k;
#pragma unroll
        for (int off = 32; off > 0; off >>= 1) ss += __shfl_xor(ss, off);
        k = k / fmaxf(sqrtf(ss), 1e-12f);

        sk[lane] = k;
        sq[lane] = q;
        __syncthreads();

        float p0 = 0.f, p1 = 0.f, p2 = 0.f, p3 = 0.f;
#pragma unroll
        for (int j = 0; j < 64; j += 4) {
            p0 += Wrow[j + 0] * sk[j + 0];
            p1 += Wrow[j + 1] * sk[j + 1];
            p2 += Wrow[j + 2] * sk[j + 2];
            p3 += Wrow[j + 3] * sk[j + 3];
        }
        const float bei = be * (v - ((p0 + p1) + (p2 + p3)));

        float o0 = 0.f, o1 = 0.f, o2 = 0.f, o3 = 0.f;
#pragma unroll
        for (int j = 0; j < 64; j += 4) {
            Wrow[j + 0] += bei * sk[j + 0]; o0 += Wrow[j + 0] * sq[j + 0];
            Wrow[j + 1] += bei * sk[j + 1]; o1 += Wrow[j + 1] * sq[j + 1];
            Wrow[j + 2] += bei * sk[j + 2]; o2 += Wrow[j + 2] * sq[j + 2];
            Wrow[j + 3] += bei * sk[j + 3]; o3 += Wrow[j + 3] * sq[j + 3];
        }
        O[base] = (o0 + o1) + (o2 + o3);
        __syncthreads();
    }
}

// ---------- launch ----------
extern "C" void kernel_launch(void* const* d_in, const int* in_sizes, int n_in,
                              void* d_out, int out_size, void* d_ws, size_t ws_size,
                              hipStream_t stream) {
    const float* x     = (const float*)d_in[0];
    const float* Wq    = (const float*)d_in[1];
    const float* Wk    = (const float*)d_in[2];
    const float* Wv    = (const float*)d_in[3];
    const float* Wbeta = (const float*)d_in[4];
    const float* bbeta = (const float*)d_in[5];
    const float* Wout  = (const float*)d_in[6];
    float* out = (float*)d_out;

    const size_t projElems = (size_t)MROWS * DM;
    const size_t betaBytes = (size_t)MROWS * NH * 4;
    const size_t f32Bytes  = projElems * 4;   // 32 MiB
    const size_t bf16Bytes = projElems * 2;   // 16 MiB
    const size_t need_f32  = 4 * f32Bytes + betaBytes;  // 128.5 MiB (proven available)

    char* ws = (char*)d_ws;
    size_t off = 0;
    auto alloc = [&](size_t bytes) {
        char* p = ws + off;
        off += (bytes + 255) & ~(size_t)255;
        return (void*)p;
    };

    if (ws_size >= need_f32) {
        float* Qf = (float*)alloc(f32Bytes);    // Q -> O in-place
        float* Kf = (float*)alloc(f32Bytes);    // K -> Kn; later Oh + WoutT (bf16)
        float* Vf = (float*)alloc(f32Bytes);    // V -> u_pre
        float* Wmf = (float*)alloc(f32Bytes);   // xh+weights (bf16), then w
        float* betaf = (float*)alloc(betaBytes);

        // stage-1 bf16 conversions live in the Wm buffer (dead until prepass):
        __hip_bfloat16* xh  = (__hip_bfloat16*)Wmf;                      // 16 MiB
        __hip_bfloat16* WqT = (__hip_bfloat16*)((char*)Wmf + bf16Bytes); // 2 MiB each
        __hip_bfloat16* WkT = WqT + (size_t)DM * DM;
        __hip_bfloat16* WvT = WkT + (size_t)DM * DM;

        const int n8 = (int)(projElems / 8);
        conv_bf16<<<dim3(n8 / 256), dim3(256), 0, stream>>>(x, xh, n8);
        convT_bf16<<<dim3(16, 16), dim3(256), 0, stream>>>(Wq, WqT);
        convT_bf16<<<dim3(16, 16), dim3(256), 0, stream>>>(Wk, WkT);
        convT_bf16<<<dim3(16, 16), dim3(256), 0, stream>>>(Wv, WvT);

        const dim3 mfmaGrid(DM / 128, MROWS / 128);  // (8, 64)
        gemm_mfma<<<mfmaGrid, dim3(256), 0, stream>>>(xh, WqT, Qf, MROWS, DM, DM);
        gemm_mfma<<<mfmaGrid, dim3(256), 0, stream>>>(xh, WkT, Kf, MROWS, DM, DM);
        gemm_mfma<<<mfmaGrid, dim3(256), 0, stream>>>(xh, WvT, Vf, MROWS, DM, DM);
        beta_kernel<<<dim3(MROWS / 16), dim3(256), 0, stream>>>(x, Wbeta, bbeta, betaf);

        delta_prepass<<<dim3(TSEQ / CHUNK, BATCH * NH), dim3(256), 0, stream>>>(Kf, Vf, betaf, Wmf);
        scan_seq<<<dim3(BATCH * NH), dim3(256), 0, stream>>>(Qf, Kf, Vf, Wmf);

        // stage-2: O (in Qf) -> bf16, Wout -> transposed bf16; both in Kf (dead)
        __hip_bfloat16* Oh    = (__hip_bfloat16*)Kf;
        __hip_bfloat16* WoutT = (__hip_bfloat16*)((char*)Kf + bf16Bytes);
        conv_bf16<<<dim3(n8 / 256), dim3(256), 0, stream>>>(Qf, Oh, n8);
        convT_bf16<<<dim3(16, 16), dim3(256), 0, stream>>>(Wout, WoutT);
        gemm_mfma<<<mfmaGrid, dim3(256), 0, stream>>>(Oh, WoutT, out, MROWS, DM, DM);
    } else {
        __hip_bfloat16* Qh = (__hip_bfloat16*)alloc(bf16Bytes);
        __hip_bfloat16* Kh = (__hip_bfloat16*)alloc(bf16Bytes);
        __hip_bfloat16* Vh = (__hip_bfloat16*)alloc(bf16Bytes);
        float* betaf = (float*)alloc(betaBytes);
        float* Of = (float*)alloc(f32Bytes);

        const dim3 gemmGrid(DM / BN, MROWS / BM);
        gemm_kernel<float, __hip_bfloat16><<<gemmGrid, dim3(256), 0, stream>>>(x, Wq, Qh, MROWS, DM, DM);
        gemm_kernel<float, __hip_bfloat16><<<gemmGrid, dim3(256), 0, stream>>>(x, Wk, Kh, MROWS, DM, DM);
        gemm_kernel<float, __hip_bfloat16><<<gemmGrid, dim3(256), 0, stream>>>(x, Wv, Vh, MROWS, DM, DM);
        beta_kernel<<<dim3(MROWS / 16), dim3(256), 0, stream>>>(x, Wbeta, bbeta, betaf);
        scan_kernel<__hip_bfloat16><<<dim3(BATCH * NH), dim3(64), 0, stream>>>(Qh, Kh, Vh, betaf, Of);
        gemm_kernel<float, float><<<gemmGrid, dim3(256), 0, stream>>>(Of, Wout, out, MROWS, DM, DM);
    }
}

// Round 5
// 563.186 us; speedup vs baseline: 8.7685x; 1.6966x over previous
//
#include <hip/hip_runtime.h>
#include <hip/hip_bf16.h>

// Problem constants (fixed by the reference)
#define BATCH 4
#define TSEQ 2048
#define DM 1024
#define NH 16
#define DH 64
#define MROWS (BATCH * TSEQ)  // 8192
#define CHUNK 64
#define NCHUNK (TSEQ / CHUNK)  // 32
#define LP 65
#define RP 132

typedef __attribute__((ext_vector_type(8))) short bf16x8;
typedef __attribute__((ext_vector_type(4))) float f32x4;

#define GLOAD16(g, l)                                                        \
    __builtin_amdgcn_global_load_lds(                                        \
        (const __attribute__((address_space(1))) void*)(g),                  \
        (__attribute__((address_space(3))) void*)(l), 16, 0, 0)

// ---------- type helpers ----------
__device__ __forceinline__ float ldf(const float* p) { return *p; }
__device__ __forceinline__ float ldf(const __hip_bfloat16* p) { return __bfloat162float(*p); }
__device__ __forceinline__ void stf(float* p, float v) { *p = v; }
__device__ __forceinline__ void stf(__hip_bfloat16* p, float v) { *p = __float2bfloat16(v); }

// ---------- LDS 64x64 bf16 tile helpers (row = 128 B, XOR swizzle both sides) ----------
__device__ __forceinline__ int swz(int row, int cb) {
    return row * 128 + (cb ^ ((row & 7) << 4));
}
// MFMA fragment read: rows rowblk*16+(lane&15), k-frag kf (k = kf*32 + (lane>>4)*8 ..+8)
__device__ __forceinline__ bf16x8 ldfrag(const __hip_bfloat16* b, int rowblk, int kf, int lane) {
    const int row = rowblk * 16 + (lane & 15);
    const int cb = kf * 64 + ((lane >> 4) << 4);
    return *(const bf16x8*)((const char*)b + swz(row, cb));
}
__device__ __forceinline__ unsigned short bfbits(float f) {
    __hip_bfloat16 h = __float2bfloat16(f);
    return *(unsigned short*)&h;
}

// ================= bf16 MFMA GEMM (unchanged from R4) =================
__global__ __launch_bounds__(256) void gemm_mfma(const __hip_bfloat16* __restrict__ Ah,
                                                 const __hip_bfloat16* __restrict__ BT,
                                                 float* __restrict__ C,
                                                 int M, int N, int K) {
    __shared__ __align__(16) __hip_bfloat16 As[128 * 32];
    __shared__ __align__(16) __hip_bfloat16 Bs[128 * 32];
    const int tid = threadIdx.x;
    const int wave = tid >> 6;
    const int lane = tid & 63;
    const int wr = wave >> 1;
    const int wc = wave & 1;
    const int rowBase = blockIdx.y * 128;
    const int colBase = blockIdx.x * 128;

    f32x4 acc[4][4] = {};

    const int r0 = wave * 16 + (lane >> 2);
    const int r1 = r0 + 64;
    const int sl = lane & 3;
    const int sg0 = (sl - (r0 >> 1)) & 3;
    const int sg1 = (sl - (r1 >> 1)) & 3;
    const size_t Kz = (size_t)K;

    int offA[4], offB[4];
#pragma unroll
    for (int i = 0; i < 4; ++i) {
        const int rowa = wr * 64 + i * 16 + (lane & 15);
        const int rowb = wc * 64 + i * 16 + (lane & 15);
        offA[i] = rowa * 64 + ((((lane >> 4) + (rowa >> 1)) & 3) * 16);
        offB[i] = rowb * 64 + ((((lane >> 4) + (rowb >> 1)) & 3) * 16);
    }

    for (int k0 = 0; k0 < K; k0 += 32) {
        const __hip_bfloat16* ga0 = Ah + ((size_t)(rowBase + r0) * Kz + k0 + sg0 * 8);
        const __hip_bfloat16* ga1 = Ah + ((size_t)(rowBase + r1) * Kz + k0 + sg1 * 8);
        const __hip_bfloat16* gb0 = BT + ((size_t)(colBase + r0) * Kz + k0 + sg0 * 8);
        const __hip_bfloat16* gb1 = BT + ((size_t)(colBase + r1) * Kz + k0 + sg1 * 8);
        char* lA = (char*)As + wave * 1024;
        char* lB = (char*)Bs + wave * 1024;
        GLOAD16(ga0, lA);
        GLOAD16(ga1, lA + 4096);
        GLOAD16(gb0, lB);
        GLOAD16(gb1, lB + 4096);
        __syncthreads();

        bf16x8 af[4], bfr[4];
#pragma unroll
        for (int i = 0; i < 4; ++i) af[i] = *(const bf16x8*)((const char*)As + offA[i]);
#pragma unroll
        for (int i = 0; i < 4; ++i) bfr[i] = *(const bf16x8*)((const char*)Bs + offB[i]);
#pragma unroll
        for (int mi = 0; mi < 4; ++mi)
#pragma unroll
            for (int ni = 0; ni < 4; ++ni)
                acc[mi][ni] =
                    __builtin_amdgcn_mfma_f32_16x16x32_bf16(af[mi], bfr[ni], acc[mi][ni], 0, 0, 0);
        __syncthreads();
    }

#pragma unroll
    for (int mi = 0; mi < 4; ++mi)
#pragma unroll
        for (int ni = 0; ni < 4; ++ni) {
            const int col = colBase + wc * 64 + ni * 16 + (lane & 15);
#pragma unroll
            for (int r = 0; r < 4; ++r) {
                const int row = rowBase + wr * 64 + mi * 16 + (lane >> 4) * 4 + r;
                C[(size_t)row * N + col] = acc[mi][ni][r];
            }
        }
}

// ---------- conversions (unchanged) ----------
__global__ __launch_bounds__(256) void conv_bf16(const float* __restrict__ in,
                                                 __hip_bfloat16* __restrict__ out, int n8) {
    const int i = blockIdx.x * 256 + threadIdx.x;
    if (i >= n8) return;
    const float4* p = (const float4*)in + (size_t)i * 2;
    float4 a = p[0], b = p[1];
    __hip_bfloat16 t[8] = {__float2bfloat16(a.x), __float2bfloat16(a.y),
                           __float2bfloat16(a.z), __float2bfloat16(a.w),
                           __float2bfloat16(b.x), __float2bfloat16(b.y),
                           __float2bfloat16(b.z), __float2bfloat16(b.w)};
    *(uint4*)(out + (size_t)i * 8) = *(const uint4*)t;
}

__global__ __launch_bounds__(256) void convT_bf16(const float* __restrict__ W,
                                                  __hip_bfloat16* __restrict__ WT) {
    __shared__ __hip_bfloat16 tile[64][65];
    const int tid = threadIdx.x;
    const int c = tid & 63;
    const int r4 = tid >> 6;
    const int kb = blockIdx.y * 64;
    const int nb = blockIdx.x * 64;
#pragma unroll
    for (int i = 0; i < 16; ++i) {
        const int r = r4 + i * 4;
        tile[r][c] = __float2bfloat16(W[(size_t)(kb + r) * DM + nb + c]);
    }
    __syncthreads();
#pragma unroll
    for (int i = 0; i < 16; ++i) {
        const int r = r4 + i * 4;
        WT[(size_t)(nb + r) * DM + kb + c] = tile[c][r];
    }
}

// ---------- beta (unchanged) ----------
__global__ __launch_bounds__(256) void beta_kernel(const float* __restrict__ x,
                                                   const float* __restrict__ Wb,
                                                   const float* __restrict__ bb,
                                                   float* __restrict__ beta) {
    const int tid = threadIdx.x;
    const int h = tid % NH;
    const int rl = tid / NH;
    const int row = blockIdx.x * 16 + rl;
    const float* xr = x + (size_t)row * DM;
    float acc = 0.f;
#pragma unroll 8
    for (int k = 0; k < DM; ++k) acc += xr[k] * Wb[k * NH + h];
    acc += bb[h];
    beta[row * NH + h] = 1.f / (1.f + __expf(-acc));
}

__device__ __forceinline__ void fma44(float (&acc)[4][4], const float* a, const float* b) {
#pragma unroll
    for (int m = 0; m < 4; ++m)
#pragma unroll
        for (int n = 0; n < 4; ++n) acc[m][n] += a[m] * b[n];
}

// ---------- Kernel A: chunk-local pre-pass (unchanged from R4) ----------
__global__ __launch_bounds__(256) void delta_prepass(float* __restrict__ K,
                                                     float* __restrict__ V,
                                                     const float* __restrict__ beta,
                                                     float* __restrict__ Wm) {
    const int chunk = blockIdx.x;
    const int bh = blockIdx.y;
    const int b = bh >> 4;
    const int h = bh & 15;
    const int tid = threadIdx.x;
    const int tr = tid >> 4;
    const int tc = tid & 15;
    const int lt = tid >> 2;
    const int j0 = (tid & 3) * 16;
    const int c0 = chunk * CHUNK;

    __shared__ __align__(16) float Kn[CHUNK][LP];
    __shared__ __align__(16) float Am[CHUNK][LP];
    __shared__ __align__(16) float RHS[CHUNK][RP];
    __shared__ float sbeta[CHUNK];

    const size_t gstride = NH * DH;
    const size_t gbase = (size_t)b * TSEQ * gstride + (size_t)h * DH;
    float* kp = K + gbase + (size_t)(c0 + lt) * gstride + j0;
    float* vp = V + gbase + (size_t)(c0 + lt) * gstride + j0;

    float4 k0 = ((const float4*)kp)[0];
    float4 k1 = ((const float4*)kp)[1];
    float4 k2 = ((const float4*)kp)[2];
    float4 k3 = ((const float4*)kp)[3];
    float ss = k0.x * k0.x + k0.y * k0.y + k0.z * k0.z + k0.w * k0.w +
               k1.x * k1.x + k1.y * k1.y + k1.z * k1.z + k1.w * k1.w +
               k2.x * k2.x + k2.y * k2.y + k2.z * k2.z + k2.w * k2.w +
               k3.x * k3.x + k3.y * k3.y + k3.z * k3.z + k3.w * k3.w;
    ss += __shfl_xor(ss, 1);
    ss += __shfl_xor(ss, 2);
    const float rn = 1.f / fmaxf(sqrtf(ss), 1e-12f);
    k0.x *= rn; k0.y *= rn; k0.z *= rn; k0.w *= rn;
    k1.x *= rn; k1.y *= rn; k1.z *= rn; k1.w *= rn;
    k2.x *= rn; k2.y *= rn; k2.z *= rn; k2.w *= rn;
    k3.x *= rn; k3.y *= rn; k3.z *= rn; k3.w *= rn;
    ((float4*)kp)[0] = k0; ((float4*)kp)[1] = k1;
    ((float4*)kp)[2] = k2; ((float4*)kp)[3] = k3;
    Kn[lt][j0 + 0] = k0.x;  Kn[lt][j0 + 1] = k0.y;  Kn[lt][j0 + 2] = k0.z;  Kn[lt][j0 + 3] = k0.w;
    Kn[lt][j0 + 4] = k1.x;  Kn[lt][j0 + 5] = k1.y;  Kn[lt][j0 + 6] = k1.z;  Kn[lt][j0 + 7] = k1.w;
    Kn[lt][j0 + 8] = k2.x;  Kn[lt][j0 + 9] = k2.y;  Kn[lt][j0 + 10] = k2.z; Kn[lt][j0 + 11] = k2.w;
    Kn[lt][j0 + 12] = k3.x; Kn[lt][j0 + 13] = k3.y; Kn[lt][j0 + 14] = k3.z; Kn[lt][j0 + 15] = k3.w;

    float4 v0 = ((const float4*)vp)[0];
    float4 v1 = ((const float4*)vp)[1];
    float4 v2 = ((const float4*)vp)[2];
    float4 v3 = ((const float4*)vp)[3];

    if (tid < CHUNK)
        sbeta[tid] = beta[((size_t)(b * TSEQ + c0 + tid)) * NH + h];
    __syncthreads();

    {
        float acc[4][4];
#pragma unroll
        for (int m = 0; m < 4; ++m)
#pragma unroll
            for (int n = 0; n < 4; ++n) acc[m][n] = 0.f;
#pragma unroll 8
        for (int kk = 0; kk < DH; ++kk) {
            float a[4], bb2[4];
#pragma unroll
            for (int m = 0; m < 4; ++m) a[m] = Kn[tr * 4 + m][kk];
#pragma unroll
            for (int n = 0; n < 4; ++n) bb2[n] = Kn[tc * 4 + n][kk];
            fma44(acc, a, bb2);
        }
#pragma unroll
        for (int m = 0; m < 4; ++m) {
            const float bt = sbeta[tr * 4 + m];
#pragma unroll
            for (int n = 0; n < 4; ++n) Am[tr * 4 + m][tc * 4 + n] = bt * acc[m][n];
        }
    }
    {
        const float bl = sbeta[lt];
        *(float4*)&RHS[lt][j0 + 0]  = make_float4(bl * v0.x, bl * v0.y, bl * v0.z, bl * v0.w);
        *(float4*)&RHS[lt][j0 + 4]  = make_float4(bl * v1.x, bl * v1.y, bl * v1.z, bl * v1.w);
        *(float4*)&RHS[lt][j0 + 8]  = make_float4(bl * v2.x, bl * v2.y, bl * v2.z, bl * v2.w);
        *(float4*)&RHS[lt][j0 + 12] = make_float4(bl * v3.x, bl * v3.y, bl * v3.z, bl * v3.w);
        *(float4*)&RHS[lt][64 + j0 + 0]  = make_float4(bl * k0.x, bl * k0.y, bl * k0.z, bl * k0.w);
        *(float4*)&RHS[lt][64 + j0 + 4]  = make_float4(bl * k1.x, bl * k1.y, bl * k1.z, bl * k1.w);
        *(float4*)&RHS[lt][64 + j0 + 8]  = make_float4(bl * k2.x, bl * k2.y, bl * k2.z, bl * k2.w);
        *(float4*)&RHS[lt][64 + j0 + 12] = make_float4(bl * k3.x, bl * k3.y, bl * k3.z, bl * k3.w);
    }
    __syncthreads();

    const int grow = tid >> 2;
    const int gc = (tid & 3) * 32;
    for (int t = 0; t < CHUNK - 1; ++t) {
        if (grow > t) {
            const float art = Am[grow][t];
#pragma unroll
            for (int c = 0; c < 32; c += 4) {
                float4 rt = *(const float4*)&RHS[t][gc + c];
                float4 rr = *(float4*)&RHS[grow][gc + c];
                rr.x -= art * rt.x; rr.y -= art * rt.y;
                rr.z -= art * rt.z; rr.w -= art * rt.w;
                *(float4*)&RHS[grow][gc + c] = rr;
            }
        }
        __syncthreads();
    }

    float* wp = Wm + gbase + (size_t)(c0 + lt) * gstride + j0;
#pragma unroll
    for (int q = 0; q < 4; ++q) {
        ((float4*)vp)[q] = *(const float4*)&RHS[lt][j0 + 4 * q];
        ((float4*)wp)[q] = *(const float4*)&RHS[lt][64 + j0 + 4 * q];
    }
}

// ---------- Kernel B: thin sequential scan (MFMA, S fp32 in accumulators) ----------
// Per chunk: snapshot S (bf16); U = u_pre - w.S^T; S += U^T.Kn; dump Ut (bf16).
__global__ __launch_bounds__(256) void scan_thin(const float* __restrict__ Kg,   // Kn fp32
                                                 const float* __restrict__ Ug,   // u_pre fp32
                                                 const float* __restrict__ Wg,   // w fp32
                                                 __hip_bfloat16* __restrict__ Sg,
                                                 __hip_bfloat16* __restrict__ Utg) {
    const int bh = blockIdx.x;
    const int b = bh >> 4;
    const int h = bh & 15;
    const int tid = threadIdx.x;
    const int wave = tid >> 6;
    const int lane = tid & 63;
    const int srow = tid >> 2;          // 0..63 staging row
    const int sj0 = (tid & 3) * 16;     // staging col quarter

    __shared__ __align__(16) __hip_bfloat16 wb[2][64 * 64];
    __shared__ __align__(16) __hip_bfloat16 knT[2][64 * 64];
    __shared__ __align__(16) __hip_bfloat16 Sb[64 * 64];
    __shared__ __align__(16) __hip_bfloat16 Ut[64 * 64];

    const size_t gstride = NH * DH;
    const size_t gbase = (size_t)b * TSEQ * gstride + (size_t)h * DH;
    const size_t tileBase = (size_t)bh * NCHUNK;  // in 4096-elem tiles

    // zero Sb
    for (int i = tid; i < 512; i += 256) ((uint4*)Sb)[i] = make_uint4(0, 0, 0, 0);

    // stage chunk 0: wb[0], knT[0]
    {
        const float4* wp = (const float4*)(Wg + gbase + (size_t)srow * gstride + sj0);
        __hip_bfloat16 t[16];
#pragma unroll
        for (int q = 0; q < 4; ++q) {
            float4 v = wp[q];
            t[q * 4 + 0] = __float2bfloat16(v.x); t[q * 4 + 1] = __float2bfloat16(v.y);
            t[q * 4 + 2] = __float2bfloat16(v.z); t[q * 4 + 3] = __float2bfloat16(v.w);
        }
        *(uint4*)((char*)wb[0] + swz(srow, sj0 * 2)) = *(const uint4*)&t[0];
        *(uint4*)((char*)wb[0] + swz(srow, sj0 * 2 + 16)) = *(const uint4*)&t[8];
        const float4* kp = (const float4*)(Kg + gbase + (size_t)srow * gstride + sj0);
#pragma unroll
        for (int q = 0; q < 4; ++q) {
            float4 v = kp[q];
            float vv[4] = {v.x, v.y, v.z, v.w};
#pragma unroll
            for (int e = 0; e < 4; ++e) {
                const int j = sj0 + q * 4 + e;
                *(unsigned short*)((char*)knT[0] + swz(j, srow * 2)) = bfbits(vv[e]);
            }
        }
    }

    f32x4 Sreg[4] = {};  // wave owns S rows [16*wave, 16*wave+16), 4 j-tiles
    __syncthreads();

    for (int c = 0; c < NCHUNK; ++c) {
        const int cur = c & 1;
        const size_t cOff = (size_t)(c * CHUNK);

        // ---- phase 1: snapshot Sb -> global; accU = w.S^T; U -> Ut LDS ----
        {
            uint4 a = *(const uint4*)((const char*)Sb + swz(srow, sj0 * 2));
            uint4 a2 = *(const uint4*)((const char*)Sb + swz(srow, sj0 * 2 + 16));
            __hip_bfloat16* gp = Sg + (tileBase + c) * 4096 + srow * 64 + sj0;
            *(uint4*)gp = a;
            *(uint4*)(gp + 8) = a2;
        }
        // u_pre preload
        float up[4][4];
#pragma unroll
        for (int ib = 0; ib < 4; ++ib)
#pragma unroll
            for (int r = 0; r < 4; ++r) {
                const int t = 16 * wave + (lane >> 4) * 4 + r;
                up[ib][r] = Ug[gbase + (cOff + t) * gstride + 16 * ib + (lane & 15)];
            }
        f32x4 accU[4] = {};
#pragma unroll
        for (int f = 0; f < 2; ++f) {
            bf16x8 wa = ldfrag(wb[cur], wave, f, lane);
#pragma unroll
            for (int ib = 0; ib < 4; ++ib)
                accU[ib] = __builtin_amdgcn_mfma_f32_16x16x32_bf16(
                    wa, ldfrag(Sb, ib, f, lane), accU[ib], 0, 0, 0);
        }
        // U = up - accU -> Ut[i][t] (bf16, 8B packed along t)
#pragma unroll
        for (int ib = 0; ib < 4; ++ib) {
            unsigned short pk[4];
#pragma unroll
            for (int r = 0; r < 4; ++r) pk[r] = bfbits(up[ib][r] - accU[ib][r]);
            const int irow = 16 * ib + (lane & 15);
            const int tcb = (16 * wave + (lane >> 4) * 4) * 2;
            *(unsigned long long*)((char*)Ut + swz(irow, tcb)) = *(const unsigned long long*)pk;
        }
        __syncthreads();

        // ---- phase 2: S += U^T.Kn ; dump Ut; write new Sb; stage next chunk ----
#pragma unroll
        for (int f = 0; f < 2; ++f) {
            bf16x8 ua = ldfrag(Ut, wave, f, lane);
#pragma unroll
            for (int jb = 0; jb < 4; ++jb)
                Sreg[jb] = __builtin_amdgcn_mfma_f32_16x16x32_bf16(
                    ua, ldfrag(knT[cur], jb, f, lane), Sreg[jb], 0, 0, 0);
        }
        {
            uint4 a = *(const uint4*)((const char*)Ut + swz(srow, sj0 * 2));
            uint4 a2 = *(const uint4*)((const char*)Ut + swz(srow, sj0 * 2 + 16));
            __hip_bfloat16* gp = Utg + (tileBase + c) * 4096 + srow * 64 + sj0;
            *(uint4*)gp = a;
            *(uint4*)(gp + 8) = a2;
        }
        // Sreg -> Sb bf16 (C layout: col j = lane&15 within tile, row i = (lane>>4)*4+r)
#pragma unroll
        for (int jb = 0; jb < 4; ++jb)
#pragma unroll
            for (int r = 0; r < 4; ++r) {
                const int irow = 16 * wave + (lane >> 4) * 4 + r;
                const int j = 16 * jb + (lane & 15);
                *(unsigned short*)((char*)Sb + swz(irow, j * 2)) = bfbits(Sreg[jb][r]);
            }
        if (c + 1 < NCHUNK) {
            const int nxt = cur ^ 1;
            const size_t nOff = (size_t)((c + 1) * CHUNK);
            const float4* wp = (const float4*)(Wg + gbase + (nOff + srow) * gstride + sj0);
            __hip_bfloat16 t[16];
#pragma unroll
            for (int q = 0; q < 4; ++q) {
                float4 v = wp[q];
                t[q * 4 + 0] = __float2bfloat16(v.x); t[q * 4 + 1] = __float2bfloat16(v.y);
                t[q * 4 + 2] = __float2bfloat16(v.z); t[q * 4 + 3] = __float2bfloat16(v.w);
            }
            *(uint4*)((char*)wb[nxt] + swz(srow, sj0 * 2)) = *(const uint4*)&t[0];
            *(uint4*)((char*)wb[nxt] + swz(srow, sj0 * 2 + 16)) = *(const uint4*)&t[8];
            const float4* kp = (const float4*)(Kg + gbase + (nOff + srow) * gstride + sj0);
#pragma unroll
            for (int q = 0; q < 4; ++q) {
                float4 v = kp[q];
                float vv[4] = {v.x, v.y, v.z, v.w};
#pragma unroll
                for (int e = 0; e < 4; ++e) {
                    const int j = sj0 + q * 4 + e;
                    *(unsigned short*)((char*)knT[nxt] + swz(j, srow * 2)) = bfbits(vv[e]);
                }
            }
        }
        __syncthreads();
    }
}

// ---------- Kernel C: parallel output: O = Q.S^T + tril(Q.Kn^T).U ----------
__global__ __launch_bounds__(256) void delta_output(float* __restrict__ Qf,
                                                    const float* __restrict__ Kg,
                                                    const __hip_bfloat16* __restrict__ Sg,
                                                    const __hip_bfloat16* __restrict__ Utg) {
    const int c = blockIdx.x;
    const int bh = blockIdx.y;
    const int b = bh >> 4;
    const int h = bh & 15;
    const int tid = threadIdx.x;
    const int wave = tid >> 6;
    const int lane = tid & 63;
    const int srow = tid >> 2;
    const int sj0 = (tid & 3) * 16;

    __shared__ __align__(16) __hip_bfloat16 Qb[64 * 64];
    __shared__ __align__(16) __hip_bfloat16 Knb[64 * 64];
    __shared__ __align__(16) __hip_bfloat16 Sbs[64 * 64];
    __shared__ __align__(16) __hip_bfloat16 Utb[64 * 64];
    __shared__ __align__(16) __hip_bfloat16 SSb[64 * 64];

    const size_t gstride = NH * DH;
    const size_t gbase = (size_t)b * TSEQ * gstride + (size_t)h * DH;
    const size_t cOff = (size_t)(c * CHUNK);
    const size_t tile = ((size_t)bh * NCHUNK + c) * 4096;

    // stage Q, Kn (fp32->bf16), S, Ut (bf16 copy), all swizzled
    {
        const float4* qp = (const float4*)(Qf + gbase + (cOff + srow) * gstride + sj0);
        const float4* kp = (const float4*)(Kg + gbase + (cOff + srow) * gstride + sj0);
        __hip_bfloat16 tq[16], tk[16];
#pragma unroll
        for (int q = 0; q < 4; ++q) {
            float4 a = qp[q], bb2 = kp[q];
            tq[q * 4 + 0] = __float2bfloat16(a.x); tq[q * 4 + 1] = __float2bfloat16(a.y);
            tq[q * 4 + 2] = __float2bfloat16(a.z); tq[q * 4 + 3] = __float2bfloat16(a.w);
            tk[q * 4 + 0] = __float2bfloat16(bb2.x); tk[q * 4 + 1] = __float2bfloat16(bb2.y);
            tk[q * 4 + 2] = __float2bfloat16(bb2.z); tk[q * 4 + 3] = __float2bfloat16(bb2.w);
        }
        *(uint4*)((char*)Qb + swz(srow, sj0 * 2)) = *(const uint4*)&tq[0];
        *(uint4*)((char*)Qb + swz(srow, sj0 * 2 + 16)) = *(const uint4*)&tq[8];
        *(uint4*)((char*)Knb + swz(srow, sj0 * 2)) = *(const uint4*)&tk[0];
        *(uint4*)((char*)Knb + swz(srow, sj0 * 2 + 16)) = *(const uint4*)&tk[8];
        const uint4* sp = (const uint4*)(Sg + tile + srow * 64 + sj0);
        const uint4* upp = (const uint4*)(Utg + tile + srow * 64 + sj0);
        *(uint4*)((char*)Sbs + swz(srow, sj0 * 2)) = sp[0];
        *(uint4*)((char*)Sbs + swz(srow, sj0 * 2 + 16)) = sp[1];
        *(uint4*)((char*)Utb + swz(srow, sj0 * 2)) = upp[0];
        *(uint4*)((char*)Utb + swz(srow, sj0 * 2 + 16)) = upp[1];
    }
    __syncthreads();

    // SS = Q.Kn^T ; accO = Q.S^T
    f32x4 ss[4] = {};
    f32x4 accO[4] = {};
#pragma unroll
    for (int f = 0; f < 2; ++f) {
        bf16x8 qa = ldfrag(Qb, wave, f, lane);
#pragma unroll
        for (int sb = 0; sb < 4; ++sb)
            ss[sb] = __builtin_amdgcn_mfma_f32_16x16x32_bf16(
                qa, ldfrag(Knb, sb, f, lane), ss[sb], 0, 0, 0);
#pragma unroll
        for (int ib = 0; ib < 4; ++ib)
            accO[ib] = __builtin_amdgcn_mfma_f32_16x16x32_bf16(
                qa, ldfrag(Sbs, ib, f, lane), accO[ib], 0, 0, 0);
    }
    // mask (keep t >= s) and write SSb
#pragma unroll
    for (int sb = 0; sb < 4; ++sb)
#pragma unroll
        for (int r = 0; r < 4; ++r) {
            const int t = 16 * wave + (lane >> 4) * 4 + r;
            const int s = 16 * sb + (lane & 15);
            const float v = (t >= s) ? ss[sb][r] : 0.f;
            *(unsigned short*)((char*)SSb + swz(t, s * 2)) = bfbits(v);
        }
    __syncthreads();

    // accO += SS.U
#pragma unroll
    for (int f = 0; f < 2; ++f) {
        bf16x8 sa = ldfrag(SSb, wave, f, lane);
#pragma unroll
        for (int ib = 0; ib < 4; ++ib)
            accO[ib] = __builtin_amdgcn_mfma_f32_16x16x32_bf16(
                sa, ldfrag(Utb, ib, f, lane), accO[ib], 0, 0, 0);
    }
    // write O over Qf
#pragma unroll
    for (int ib = 0; ib < 4; ++ib)
#pragma unroll
        for (int r = 0; r < 4; ++r) {
            const int t = 16 * wave + (lane >> 4) * 4 + r;
            const int i = 16 * ib + (lane & 15);
            Qf[gbase + (cOff + t) * gstride + i] = accO[ib][r];
        }
}

// ---------- legacy fp32 GEMM + sequential scan (fallback path only) ----------
#define BM 64
#define BN 64
#define BK 16

template <typename TA, typename TC>
__global__ __launch_bounds__(256) void gemm_kernel(const TA* __restrict__ A,
                                                   const float* __restrict__ B,
                                                   TC* __restrict__ C,
                                                   int M, int N, int K) {
    __shared__ float As[BK][BM + 1];
    __shared__ float Bs[BK][BN + 1];
    const int tid = threadIdx.x;
    const int tr = tid / 16;
    const int tc = tid % 16;
    const int rowBase = blockIdx.y * BM;
    const int colBase = blockIdx.x * BN;

    float acc[4][4];
#pragma unroll
    for (int m = 0; m < 4; ++m)
#pragma unroll
        for (int n = 0; n < 4; ++n) acc[m][n] = 0.f;

    for (int k0 = 0; k0 < K; k0 += BK) {
#pragma unroll
        for (int i = tid; i < BM * BK; i += 256) {
            int r = i / BK, c = i % BK;
            As[c][r] = ldf(&A[(size_t)(rowBase + r) * K + k0 + c]);
        }
#pragma unroll
        for (int i = tid; i < BK * BN; i += 256) {
            int r = i / BN, c = i % BN;
            Bs[r][c] = B[(size_t)(k0 + r) * N + colBase + c];
        }
        __syncthreads();
#pragma unroll
        for (int kk = 0; kk < BK; ++kk) {
            float a[4], b[4];
#pragma unroll
            for (int m = 0; m < 4; ++m) a[m] = As[kk][tr * 4 + m];
#pragma unroll
            for (int n = 0; n < 4; ++n) b[n] = Bs[kk][tc * 4 + n];
#pragma unroll
            for (int m = 0; m < 4; ++m)
#pragma unroll
                for (int n = 0; n < 4; ++n) acc[m][n] += a[m] * b[n];
        }
        __syncthreads();
    }
#pragma unroll
    for (int m = 0; m < 4; ++m)
#pragma unroll
        for (int n = 0; n < 4; ++n)
            stf(&C[(size_t)(rowBase + tr * 4 + m) * N + colBase + tc * 4 + n], acc[m][n]);
}

template <typename TS>
__global__ __launch_bounds__(64) void scan_kernel(const TS* __restrict__ Q,
                                                  const TS* __restrict__ K,
                                                  const TS* __restrict__ V,
                                                  const float* __restrict__ beta,
                                                  float* __restrict__ O) {
    const int bh = blockIdx.x;
    const int b = bh >> 4;
    const int h = bh & 15;
    const int lane = threadIdx.x;

    float Wrow[64];
#pragma unroll
    for (int j = 0; j < 64; ++j) Wrow[j] = 0.f;

    __shared__ float sk[64];
    __shared__ float sq[64];

    size_t base = ((size_t)b * TSEQ) * (NH * DH) + h * DH + lane;
    int brow = b * TSEQ;

    for (int t = 0; t < TSEQ; ++t, base += NH * DH) {
        float k = ldf(&K[base]);
        float q = ldf(&Q[base]);
        float v = ldf(&V[base]);
        float be = beta[(size_t)(brow + t) * NH + h];

        float ss = k * k;
#pragma unroll
        for (int off = 32; off > 0; off >>= 1) ss += __shfl_xor(ss, off);
        k = k / fmaxf(sqrtf(ss), 1e-12f);

        sk[lane] = k;
        sq[lane] = q;
        __syncthreads();

        float p0 = 0.f, p1 = 0.f, p2 = 0.f, p3 = 0.f;
#pragma unroll
        for (int j = 0; j < 64; j += 4) {
            p0 += Wrow[j + 0] * sk[j + 0];
            p1 += Wrow[j + 1] * sk[j + 1];
            p2 += Wrow[j + 2] * sk[j + 2];
            p3 += Wrow[j + 3] * sk[j + 3];
        }
        const float bei = be * (v - ((p0 + p1) + (p2 + p3)));

        float o0 = 0.f, o1 = 0.f, o2 = 0.f, o3 = 0.f;
#pragma unroll
        for (int j = 0; j < 64; j += 4) {
            Wrow[j + 0] += bei * sk[j + 0]; o0 += Wrow[j + 0] * sq[j + 0];
            Wrow[j + 1] += bei * sk[j + 1]; o1 += Wrow[j + 1] * sq[j + 1];
            Wrow[j + 2] += bei * sk[j + 2]; o2 += Wrow[j + 2] * sq[j + 2];
            Wrow[j + 3] += bei * sk[j + 3]; o3 += Wrow[j + 3] * sq[j + 3];
        }
        O[base] = (o0 + o1) + (o2 + o3);
        __syncthreads();
    }
}

// ---------- launch ----------
extern "C" void kernel_launch(void* const* d_in, const int* in_sizes, int n_in,
                              void* d_out, int out_size, void* d_ws, size_t ws_size,
                              hipStream_t stream) {
    const float* x     = (const float*)d_in[0];
    const float* Wq    = (const float*)d_in[1];
    const float* Wk    = (const float*)d_in[2];
    const float* Wv    = (const float*)d_in[3];
    const float* Wbeta = (const float*)d_in[4];
    const float* bbeta = (const float*)d_in[5];
    const float* Wout  = (const float*)d_in[6];
    float* out = (float*)d_out;

    const size_t projElems = (size_t)MROWS * DM;
    const size_t betaBytes = (size_t)MROWS * NH * 4;
    const size_t f32Bytes  = projElems * 4;
    const size_t bf16Bytes = projElems * 2;
    const size_t need_f32  = 4 * f32Bytes + betaBytes;

    char* ws = (char*)d_ws;
    size_t off = 0;
    auto alloc = [&](size_t bytes) {
        char* p = ws + off;
        off += (bytes + 255) & ~(size_t)255;
        return (void*)p;
    };

    if (ws_size >= need_f32) {
        float* Qf = (float*)alloc(f32Bytes);    // Q -> O in-place
        float* Kf = (float*)alloc(f32Bytes);    // K -> Kn; later Oh + WoutT
        float* Vf = (float*)alloc(f32Bytes);    // V -> u_pre
        float* Wmf = (float*)alloc(f32Bytes);   // bf16 staging, then w
        float* betaf = (float*)alloc(betaBytes);

        __hip_bfloat16* xh  = (__hip_bfloat16*)Wmf;
        __hip_bfloat16* WqT = (__hip_bfloat16*)((char*)Wmf + bf16Bytes);
        __hip_bfloat16* WkT = WqT + (size_t)DM * DM;
        __hip_bfloat16* WvT = WkT + (size_t)DM * DM;

        const int n8 = (int)(projElems / 8);
        conv_bf16<<<dim3(n8 / 256), dim3(256), 0, stream>>>(x, xh, n8);
        convT_bf16<<<dim3(16, 16), dim3(256), 0, stream>>>(Wq, WqT);
        convT_bf16<<<dim3(16, 16), dim3(256), 0, stream>>>(Wk, WkT);
        convT_bf16<<<dim3(16, 16), dim3(256), 0, stream>>>(Wv, WvT);

        const dim3 mfmaGrid(DM / 128, MROWS / 128);
        gemm_mfma<<<mfmaGrid, dim3(256), 0, stream>>>(xh, WqT, Qf, MROWS, DM, DM);
        gemm_mfma<<<mfmaGrid, dim3(256), 0, stream>>>(xh, WkT, Kf, MROWS, DM, DM);
        gemm_mfma<<<mfmaGrid, dim3(256), 0, stream>>>(xh, WvT, Vf, MROWS, DM, DM);
        beta_kernel<<<dim3(MROWS / 16), dim3(256), 0, stream>>>(x, Wbeta, bbeta, betaf);

        delta_prepass<<<dim3(NCHUNK, BATCH * NH), dim3(256), 0, stream>>>(Kf, Vf, betaf, Wmf);

        // d_out (32 MB) as scratch: S snapshots (16 MB) + Ut (16 MB), both bf16
        __hip_bfloat16* Sg  = (__hip_bfloat16*)d_out;
        __hip_bfloat16* Utg = Sg + (size_t)BATCH * NH * NCHUNK * 4096;
        scan_thin<<<dim3(BATCH * NH), dim3(256), 0, stream>>>(Kf, Vf, Wmf, Sg, Utg);
        delta_output<<<dim3(NCHUNK, BATCH * NH), dim3(256), 0, stream>>>(Qf, Kf, Sg, Utg);

        __hip_bfloat16* Oh    = (__hip_bfloat16*)Kf;
        __hip_bfloat16* WoutT = (__hip_bfloat16*)((char*)Kf + bf16Bytes);
        conv_bf16<<<dim3(n8 / 256), dim3(256), 0, stream>>>(Qf, Oh, n8);
        convT_bf16<<<dim3(16, 16), dim3(256), 0, stream>>>(Wout, WoutT);
        gemm_mfma<<<mfmaGrid, dim3(256), 0, stream>>>(Oh, WoutT, out, MROWS, DM, DM);
    } else {
        __hip_bfloat16* Qh = (__hip_bfloat16*)alloc(bf16Bytes);
        __hip_bfloat16* Kh = (__hip_bfloat16*)alloc(bf16Bytes);
        __hip_bfloat16* Vh = (__hip_bfloat16*)alloc(bf16Bytes);
        float* betaf = (float*)alloc(betaBytes);
        float* Of = (float*)alloc(f32Bytes);

        const dim3 gemmGrid(DM / BN, MROWS / BM);
        gemm_kernel<float, __hip_bfloat16><<<gemmGrid, dim3(256), 0, stream>>>(x, Wq, Qh, MROWS, DM, DM);
        gemm_kernel<float, __hip_bfloat16><<<gemmGrid, dim3(256), 0, stream>>>(x, Wk, Kh, MROWS, DM, DM);
        gemm_kernel<float, __hip_bfloat16><<<gemmGrid, dim3(256), 0, stream>>>(x, Wv, Vh, MROWS, DM, DM);
        beta_kernel<<<dim3(MROWS / 16), dim3(256), 0, stream>>>(x, Wbeta, bbeta, betaf);
        scan_kernel<__hip_bfloat16><<<dim3(BATCH * NH), dim3(64), 0, stream>>>(Qh, Kh, Vh, betaf, Of);
        gemm_kernel<float, float><<<gemmGrid, dim3(256), 0, stream>>>(Of, Wout, out, MROWS, DM, DM);
    }
}

// Round 6
// 455.196 us; speedup vs baseline: 10.8487x; 1.2372x over previous
//
#include <hip/hip_runtime.h>
#include <hip/hip_bf16.h>

// Problem constants (fixed by the reference)
#define BATCH 4
#define TSEQ 2048
#define DM 1024
#define NH 16
#define DH 64
#define MROWS (BATCH * TSEQ)  // 8192
#define CHUNK 64
#define NCHUNK (TSEQ / CHUNK)  // 32
#define LP 65

typedef __attribute__((ext_vector_type(8))) short bf16x8;
typedef __attribute__((ext_vector_type(4))) float f32x4;

#define GLOAD16(g, l)                                                        \
    __builtin_amdgcn_global_load_lds(                                        \
        (const __attribute__((address_space(1))) void*)(g),                  \
        (__attribute__((address_space(3))) void*)(l), 16, 0, 0)

// ---------- type helpers ----------
__device__ __forceinline__ float ldf(const float* p) { return *p; }
__device__ __forceinline__ float ldf(const __hip_bfloat16* p) { return __bfloat162float(*p); }
__device__ __forceinline__ void stf(float* p, float v) { *p = v; }
__device__ __forceinline__ void stf(__hip_bfloat16* p, float v) { *p = __float2bfloat16(v); }

// ---------- LDS 64x64 bf16 tile helpers (row = 128 B, XOR swizzle both sides) ----------
__device__ __forceinline__ int swz(int row, int cb) {
    return row * 128 + (cb ^ ((row & 7) << 4));
}
__device__ __forceinline__ bf16x8 ldfrag(const __hip_bfloat16* b, int rowblk, int kf, int lane) {
    const int row = rowblk * 16 + (lane & 15);
    const int cb = kf * 64 + ((lane >> 4) << 4);
    return *(const bf16x8*)((const char*)b + swz(row, cb));
}
__device__ __forceinline__ unsigned short bfbits(float f) {
    __hip_bfloat16 h = __float2bfloat16(f);
    return *(unsigned short*)&h;
}

// ================= bf16 MFMA GEMM (unchanged) =================
__global__ __launch_bounds__(256) void gemm_mfma(const __hip_bfloat16* __restrict__ Ah,
                                                 const __hip_bfloat16* __restrict__ BT,
                                                 float* __restrict__ C,
                                                 int M, int N, int K) {
    __shared__ __align__(16) __hip_bfloat16 As[128 * 32];
    __shared__ __align__(16) __hip_bfloat16 Bs[128 * 32];
    const int tid = threadIdx.x;
    const int wave = tid >> 6;
    const int lane = tid & 63;
    const int wr = wave >> 1;
    const int wc = wave & 1;
    const int rowBase = blockIdx.y * 128;
    const int colBase = blockIdx.x * 128;

    f32x4 acc[4][4] = {};

    const int r0 = wave * 16 + (lane >> 2);
    const int r1 = r0 + 64;
    const int sl = lane & 3;
    const int sg0 = (sl - (r0 >> 1)) & 3;
    const int sg1 = (sl - (r1 >> 1)) & 3;
    const size_t Kz = (size_t)K;

    int offA[4], offB[4];
#pragma unroll
    for (int i = 0; i < 4; ++i) {
        const int rowa = wr * 64 + i * 16 + (lane & 15);
        const int rowb = wc * 64 + i * 16 + (lane & 15);
        offA[i] = rowa * 64 + ((((lane >> 4) + (rowa >> 1)) & 3) * 16);
        offB[i] = rowb * 64 + ((((lane >> 4) + (rowb >> 1)) & 3) * 16);
    }

    for (int k0 = 0; k0 < K; k0 += 32) {
        const __hip_bfloat16* ga0 = Ah + ((size_t)(rowBase + r0) * Kz + k0 + sg0 * 8);
        const __hip_bfloat16* ga1 = Ah + ((size_t)(rowBase + r1) * Kz + k0 + sg1 * 8);
        const __hip_bfloat16* gb0 = BT + ((size_t)(colBase + r0) * Kz + k0 + sg0 * 8);
        const __hip_bfloat16* gb1 = BT + ((size_t)(colBase + r1) * Kz + k0 + sg1 * 8);
        char* lA = (char*)As + wave * 1024;
        char* lB = (char*)Bs + wave * 1024;
        GLOAD16(ga0, lA);
        GLOAD16(ga1, lA + 4096);
        GLOAD16(gb0, lB);
        GLOAD16(gb1, lB + 4096);
        __syncthreads();

        bf16x8 af[4], bfr[4];
#pragma unroll
        for (int i = 0; i < 4; ++i) af[i] = *(const bf16x8*)((const char*)As + offA[i]);
#pragma unroll
        for (int i = 0; i < 4; ++i) bfr[i] = *(const bf16x8*)((const char*)Bs + offB[i]);
#pragma unroll
        for (int mi = 0; mi < 4; ++mi)
#pragma unroll
            for (int ni = 0; ni < 4; ++ni)
                acc[mi][ni] =
                    __builtin_amdgcn_mfma_f32_16x16x32_bf16(af[mi], bfr[ni], acc[mi][ni], 0, 0, 0);
        __syncthreads();
    }

#pragma unroll
    for (int mi = 0; mi < 4; ++mi)
#pragma unroll
        for (int ni = 0; ni < 4; ++ni) {
            const int col = colBase + wc * 64 + ni * 16 + (lane & 15);
#pragma unroll
            for (int r = 0; r < 4; ++r) {
                const int row = rowBase + wr * 64 + mi * 16 + (lane >> 4) * 4 + r;
                C[(size_t)row * N + col] = acc[mi][ni][r];
            }
        }
}

// ---------- conversions (unchanged) ----------
__global__ __launch_bounds__(256) void conv_bf16(const float* __restrict__ in,
                                                 __hip_bfloat16* __restrict__ out, int n8) {
    const int i = blockIdx.x * 256 + threadIdx.x;
    if (i >= n8) return;
    const float4* p = (const float4*)in + (size_t)i * 2;
    float4 a = p[0], b = p[1];
    __hip_bfloat16 t[8] = {__float2bfloat16(a.x), __float2bfloat16(a.y),
                           __float2bfloat16(a.z), __float2bfloat16(a.w),
                           __float2bfloat16(b.x), __float2bfloat16(b.y),
                           __float2bfloat16(b.z), __float2bfloat16(b.w)};
    *(uint4*)(out + (size_t)i * 8) = *(const uint4*)t;
}

__global__ __launch_bounds__(256) void convT_bf16(const float* __restrict__ W,
                                                  __hip_bfloat16* __restrict__ WT) {
    __shared__ __hip_bfloat16 tile[64][65];
    const int tid = threadIdx.x;
    const int c = tid & 63;
    const int r4 = tid >> 6;
    const int kb = blockIdx.y * 64;
    const int nb = blockIdx.x * 64;
#pragma unroll
    for (int i = 0; i < 16; ++i) {
        const int r = r4 + i * 4;
        tile[r][c] = __float2bfloat16(W[(size_t)(kb + r) * DM + nb + c]);
    }
    __syncthreads();
#pragma unroll
    for (int i = 0; i < 16; ++i) {
        const int r = r4 + i * 4;
        WT[(size_t)(nb + r) * DM + kb + c] = tile[c][r];
    }
}

// ---------- beta (unchanged) ----------
__global__ __launch_bounds__(256) void beta_kernel(const float* __restrict__ x,
                                                   const float* __restrict__ Wb,
                                                   const float* __restrict__ bb,
                                                   float* __restrict__ beta) {
    const int tid = threadIdx.x;
    const int h = tid % NH;
    const int rl = tid / NH;
    const int row = blockIdx.x * 16 + rl;
    const float* xr = x + (size_t)row * DM;
    float acc = 0.f;
#pragma unroll 8
    for (int k = 0; k < DM; ++k) acc += xr[k] * Wb[k * NH + h];
    acc += bb[h];
    beta[row * NH + h] = 1.f / (1.f + __expf(-acc));
}

__device__ __forceinline__ void fma44(float (&acc)[4][4], const float* a, const float* b) {
#pragma unroll
    for (int m = 0; m < 4; ++m)
#pragma unroll
        for (int n = 0; n < 4; ++n) acc[m][n] += a[m] * b[n];
}

// ---------- Kernel A: chunk-local pre-pass (REWRITTEN Gauss: transposed RHS,
//            2-pivot fusion, zero-padded AmT so no masks, deferred p1 write) ----------
// RT[c][r]: c in [0,128) (cols 0-63 = beta*V, 64-127 = beta*Kn), r in [0,64).
// AmT[s][r] = A[r][s] = beta_r*(k_r.k_s) for s<r, else 0.
__global__ __launch_bounds__(256) void delta_prepass(float* __restrict__ K,
                                                     float* __restrict__ V,
                                                     const float* __restrict__ beta,
                                                     float* __restrict__ Wm) {
    const int chunk = blockIdx.x;
    const int bh = blockIdx.y;
    const int b = bh >> 4;
    const int h = bh & 15;
    const int tid = threadIdx.x;
    const int tr = tid >> 4;
    const int tc = tid & 15;
    const int lt = tid >> 2;
    const int j0 = (tid & 3) * 16;
    const int c0 = chunk * CHUNK;

    __shared__ __align__(16) float Kn[CHUNK][LP];    // [t][j] for A build
    __shared__ __align__(8) float AmT[CHUNK][66];    // [s][r], zero-padded
    __shared__ __align__(8) float RT[128][66];       // [c][r] transposed RHS
    __shared__ float sbeta[CHUNK];

    const size_t gstride = NH * DH;
    const size_t gbase = (size_t)b * TSEQ * gstride + (size_t)h * DH;
    float* kp = K + gbase + (size_t)(c0 + lt) * gstride + j0;
    float* vp = V + gbase + (size_t)(c0 + lt) * gstride + j0;

    // load K row-part, L2-normalize (row norm across 4 threads of the row)
    float4 k0 = ((const float4*)kp)[0];
    float4 k1 = ((const float4*)kp)[1];
    float4 k2 = ((const float4*)kp)[2];
    float4 k3 = ((const float4*)kp)[3];
    float ss = k0.x * k0.x + k0.y * k0.y + k0.z * k0.z + k0.w * k0.w +
               k1.x * k1.x + k1.y * k1.y + k1.z * k1.z + k1.w * k1.w +
               k2.x * k2.x + k2.y * k2.y + k2.z * k2.z + k2.w * k2.w +
               k3.x * k3.x + k3.y * k3.y + k3.z * k3.z + k3.w * k3.w;
    ss += __shfl_xor(ss, 1);
    ss += __shfl_xor(ss, 2);
    const float rn = 1.f / fmaxf(sqrtf(ss), 1e-12f);
    k0.x *= rn; k0.y *= rn; k0.z *= rn; k0.w *= rn;
    k1.x *= rn; k1.y *= rn; k1.z *= rn; k1.w *= rn;
    k2.x *= rn; k2.y *= rn; k2.z *= rn; k2.w *= rn;
    k3.x *= rn; k3.y *= rn; k3.z *= rn; k3.w *= rn;
    ((float4*)kp)[0] = k0; ((float4*)kp)[1] = k1;
    ((float4*)kp)[2] = k2; ((float4*)kp)[3] = k3;
    Kn[lt][j0 + 0] = k0.x;  Kn[lt][j0 + 1] = k0.y;  Kn[lt][j0 + 2] = k0.z;  Kn[lt][j0 + 3] = k0.w;
    Kn[lt][j0 + 4] = k1.x;  Kn[lt][j0 + 5] = k1.y;  Kn[lt][j0 + 6] = k1.z;  Kn[lt][j0 + 7] = k1.w;
    Kn[lt][j0 + 8] = k2.x;  Kn[lt][j0 + 9] = k2.y;  Kn[lt][j0 + 10] = k2.z; Kn[lt][j0 + 11] = k2.w;
    Kn[lt][j0 + 12] = k3.x; Kn[lt][j0 + 13] = k3.y; Kn[lt][j0 + 14] = k3.z; Kn[lt][j0 + 15] = k3.w;

    float4 v0 = ((const float4*)vp)[0];
    float4 v1 = ((const float4*)vp)[1];
    float4 v2 = ((const float4*)vp)[2];
    float4 v3 = ((const float4*)vp)[3];

    if (tid < CHUNK)
        sbeta[tid] = beta[((size_t)(b * TSEQ + c0 + tid)) * NH + h];
    __syncthreads();

    // AmT[s][r] = (s<r) ? beta_r * (k_r.k_s) : 0
    {
        float acc[4][4];
#pragma unroll
        for (int m = 0; m < 4; ++m)
#pragma unroll
            for (int n = 0; n < 4; ++n) acc[m][n] = 0.f;
#pragma unroll 8
        for (int kk = 0; kk < DH; ++kk) {
            float a[4], bb2[4];
#pragma unroll
            for (int m = 0; m < 4; ++m) a[m] = Kn[tr * 4 + m][kk];
#pragma unroll
            for (int n = 0; n < 4; ++n) bb2[n] = Kn[tc * 4 + n][kk];
            fma44(acc, a, bb2);
        }
#pragma unroll
        for (int m = 0; m < 4; ++m) {
            const int r = tr * 4 + m;
            const float bt = sbeta[r];
#pragma unroll
            for (int n = 0; n < 4; ++n) {
                const int s = tc * 4 + n;
                AmT[s][r] = (s < r) ? bt * acc[m][n] : 0.f;
            }
        }
    }
    // RT fill (transposed): RT[j][lt] = beta*v ; RT[64+j][lt] = beta*kn
    {
        const float bl = sbeta[lt];
        float vv[16] = {v0.x, v0.y, v0.z, v0.w, v1.x, v1.y, v1.z, v1.w,
                        v2.x, v2.y, v2.z, v2.w, v3.x, v3.y, v3.z, v3.w};
        float kk[16] = {k0.x, k0.y, k0.z, k0.w, k1.x, k1.y, k1.z, k1.w,
                        k2.x, k2.y, k2.z, k2.w, k3.x, k3.y, k3.z, k3.w};
#pragma unroll
        for (int e = 0; e < 16; ++e) {
            RT[j0 + e][lt] = bl * vv[e];
            RT[64 + j0 + e][lt] = bl * kk[e];
        }
    }
    __syncthreads();

    // Fused 2-pivot forward elimination, 32 steps.
    // Thread owns column c = tid>>1 and row-pairs p ≡ (tid&1) (mod 2).
    {
        const int c = tid >> 1;
        const int hh = tid & 1;
        float defer = 0.f;
        for (int t = 0; t < CHUNK; t += 2) {
            if (t > 0) RT[c][t - 1] = defer;  // finalized p1 of previous step (post-barrier)
            const float p0 = RT[c][t];
            const float p1 = RT[c][t + 1] - AmT[t][t + 1] * p0;
            int p = (t >> 1) + 1;
            if ((p & 1) != hh) ++p;
            for (; p < 32; p += 2) {
                float2 a = *(const float2*)&AmT[t][2 * p];
                float2 bq = *(const float2*)&AmT[t + 1][2 * p];
                float2 v = *(float2*)&RT[c][2 * p];
                v.x -= a.x * p0 + bq.x * p1;
                v.y -= a.y * p0 + bq.y * p1;
                *(float2*)&RT[c][2 * p] = v;
            }
            defer = p1;
            __syncthreads();
        }
        RT[c][CHUNK - 1] = defer;
    }
    __syncthreads();

    // write u (over V) and w (row-major from transposed RT)
    {
        float uu[16], ww[16];
#pragma unroll
        for (int e = 0; e < 16; ++e) {
            uu[e] = RT[j0 + e][lt];
            ww[e] = RT[64 + j0 + e][lt];
        }
        float* wp = Wm + gbase + (size_t)(c0 + lt) * gstride + j0;
#pragma unroll
        for (int q = 0; q < 4; ++q) {
            ((float4*)vp)[q] = make_float4(uu[q * 4 + 0], uu[q * 4 + 1], uu[q * 4 + 2], uu[q * 4 + 3]);
            ((float4*)wp)[q] = make_float4(ww[q * 4 + 0], ww[q * 4 + 1], ww[q * 4 + 2], ww[q * 4 + 3]);
        }
    }
}

// ---------- Kernel B: thin sequential scan (unchanged) ----------
__global__ __launch_bounds__(256) void scan_thin(const float* __restrict__ Kg,
                                                 const float* __restrict__ Ug,
                                                 const float* __restrict__ Wg,
                                                 __hip_bfloat16* __restrict__ Sg,
                                                 __hip_bfloat16* __restrict__ Utg) {
    const int bh = blockIdx.x;
    const int b = bh >> 4;
    const int h = bh & 15;
    const int tid = threadIdx.x;
    const int wave = tid >> 6;
    const int lane = tid & 63;
    const int srow = tid >> 2;
    const int sj0 = (tid & 3) * 16;

    __shared__ __align__(16) __hip_bfloat16 wb[2][64 * 64];
    __shared__ __align__(16) __hip_bfloat16 knT[2][64 * 64];
    __shared__ __align__(16) __hip_bfloat16 Sb[64 * 64];
    __shared__ __align__(16) __hip_bfloat16 Ut[64 * 64];

    const size_t gstride = NH * DH;
    const size_t gbase = (size_t)b * TSEQ * gstride + (size_t)h * DH;
    const size_t tileBase = (size_t)bh * NCHUNK;

    for (int i = tid; i < 512; i += 256) ((uint4*)Sb)[i] = make_uint4(0, 0, 0, 0);

    {
        const float4* wp = (const float4*)(Wg + gbase + (size_t)srow * gstride + sj0);
        __hip_bfloat16 t[16];
#pragma unroll
        for (int q = 0; q < 4; ++q) {
            float4 v = wp[q];
            t[q * 4 + 0] = __float2bfloat16(v.x); t[q * 4 + 1] = __float2bfloat16(v.y);
            t[q * 4 + 2] = __float2bfloat16(v.z); t[q * 4 + 3] = __float2bfloat16(v.w);
        }
        *(uint4*)((char*)wb[0] + swz(srow, sj0 * 2)) = *(const uint4*)&t[0];
        *(uint4*)((char*)wb[0] + swz(srow, sj0 * 2 + 16)) = *(const uint4*)&t[8];
        const float4* kp = (const float4*)(Kg + gbase + (size_t)srow * gstride + sj0);
#pragma unroll
        for (int q = 0; q < 4; ++q) {
            float4 v = kp[q];
            float vv[4] = {v.x, v.y, v.z, v.w};
#pragma unroll
            for (int e = 0; e < 4; ++e) {
                const int j = sj0 + q * 4 + e;
                *(unsigned short*)((char*)knT[0] + swz(j, srow * 2)) = bfbits(vv[e]);
            }
        }
    }

    f32x4 Sreg[4] = {};
    __syncthreads();

    for (int c = 0; c < NCHUNK; ++c) {
        const int cur = c & 1;
        const size_t cOff = (size_t)(c * CHUNK);

        {
            uint4 a = *(const uint4*)((const char*)Sb + swz(srow, sj0 * 2));
            uint4 a2 = *(const uint4*)((const char*)Sb + swz(srow, sj0 * 2 + 16));
            __hip_bfloat16* gp = Sg + (tileBase + c) * 4096 + srow * 64 + sj0;
            *(uint4*)gp = a;
            *(uint4*)(gp + 8) = a2;
        }
        float up[4][4];
#pragma unroll
        for (int ib = 0; ib < 4; ++ib)
#pragma unroll
            for (int r = 0; r < 4; ++r) {
                const int t = 16 * wave + (lane >> 4) * 4 + r;
                up[ib][r] = Ug[gbase + (cOff + t) * gstride + 16 * ib + (lane & 15)];
            }
        f32x4 accU[4] = {};
#pragma unroll
        for (int f = 0; f < 2; ++f) {
            bf16x8 wa = ldfrag(wb[cur], wave, f, lane);
#pragma unroll
            for (int ib = 0; ib < 4; ++ib)
                accU[ib] = __builtin_amdgcn_mfma_f32_16x16x32_bf16(
                    wa, ldfrag(Sb, ib, f, lane), accU[ib], 0, 0, 0);
        }
#pragma unroll
        for (int ib = 0; ib < 4; ++ib) {
            unsigned short pk[4];
#pragma unroll
            for (int r = 0; r < 4; ++r) pk[r] = bfbits(up[ib][r] - accU[ib][r]);
            const int irow = 16 * ib + (lane & 15);
            const int tcb = (16 * wave + (lane >> 4) * 4) * 2;
            *(unsigned long long*)((char*)Ut + swz(irow, tcb)) = *(const unsigned long long*)pk;
        }
        __syncthreads();

#pragma unroll
        for (int f = 0; f < 2; ++f) {
            bf16x8 ua = ldfrag(Ut, wave, f, lane);
#pragma unroll
            for (int jb = 0; jb < 4; ++jb)
                Sreg[jb] = __builtin_amdgcn_mfma_f32_16x16x32_bf16(
                    ua, ldfrag(knT[cur], jb, f, lane), Sreg[jb], 0, 0, 0);
        }
        {
            uint4 a = *(const uint4*)((const char*)Ut + swz(srow, sj0 * 2));
            uint4 a2 = *(const uint4*)((const char*)Ut + swz(srow, sj0 * 2 + 16));
            __hip_bfloat16* gp = Utg + (tileBase + c) * 4096 + srow * 64 + sj0;
            *(uint4*)gp = a;
            *(uint4*)(gp + 8) = a2;
        }
#pragma unroll
        for (int jb = 0; jb < 4; ++jb)
#pragma unroll
            for (int r = 0; r < 4; ++r) {
                const int irow = 16 * wave + (lane >> 4) * 4 + r;
                const int j = 16 * jb + (lane & 15);
                *(unsigned short*)((char*)Sb + swz(irow, j * 2)) = bfbits(Sreg[jb][r]);
            }
        if (c + 1 < NCHUNK) {
            const int nxt = cur ^ 1;
            const size_t nOff = (size_t)((c + 1) * CHUNK);
            const float4* wp = (const float4*)(Wg + gbase + (nOff + srow) * gstride + sj0);
            __hip_bfloat16 t[16];
#pragma unroll
            for (int q = 0; q < 4; ++q) {
                float4 v = wp[q];
                t[q * 4 + 0] = __float2bfloat16(v.x); t[q * 4 + 1] = __float2bfloat16(v.y);
                t[q * 4 + 2] = __float2bfloat16(v.z); t[q * 4 + 3] = __float2bfloat16(v.w);
            }
            *(uint4*)((char*)wb[nxt] + swz(srow, sj0 * 2)) = *(const uint4*)&t[0];
            *(uint4*)((char*)wb[nxt] + swz(srow, sj0 * 2 + 16)) = *(const uint4*)&t[8];
            const float4* kp = (const float4*)(Kg + gbase + (nOff + srow) * gstride + sj0);
#pragma unroll
            for (int q = 0; q < 4; ++q) {
                float4 v = kp[q];
                float vv[4] = {v.x, v.y, v.z, v.w};
#pragma unroll
                for (int e = 0; e < 4; ++e) {
                    const int j = sj0 + q * 4 + e;
                    *(unsigned short*)((char*)knT[nxt] + swz(j, srow * 2)) = bfbits(vv[e]);
                }
            }
        }
        __syncthreads();
    }
}

// ---------- Kernel C: parallel output (unchanged) ----------
__global__ __launch_bounds__(256) void delta_output(float* __restrict__ Qf,
                                                    const float* __restrict__ Kg,
                                                    const __hip_bfloat16* __restrict__ Sg,
                                                    const __hip_bfloat16* __restrict__ Utg) {
    const int c = blockIdx.x;
    const int bh = blockIdx.y;
    const int b = bh >> 4;
    const int h = bh & 15;
    const int tid = threadIdx.x;
    const int wave = tid >> 6;
    const int lane = tid & 63;
    const int srow = tid >> 2;
    const int sj0 = (tid & 3) * 16;

    __shared__ __align__(16) __hip_bfloat16 Qb[64 * 64];
    __shared__ __align__(16) __hip_bfloat16 Knb[64 * 64];
    __shared__ __align__(16) __hip_bfloat16 Sbs[64 * 64];
    __shared__ __align__(16) __hip_bfloat16 Utb[64 * 64];
    __shared__ __align__(16) __hip_bfloat16 SSb[64 * 64];

    const size_t gstride = NH * DH;
    const size_t gbase = (size_t)b * TSEQ * gstride + (size_t)h * DH;
    const size_t cOff = (size_t)(c * CHUNK);
    const size_t tile = ((size_t)bh * NCHUNK + c) * 4096;

    {
        const float4* qp = (const float4*)(Qf + gbase + (cOff + srow) * gstride + sj0);
        const float4* kp = (const float4*)(Kg + gbase + (cOff + srow) * gstride + sj0);
        __hip_bfloat16 tq[16], tk[16];
#pragma unroll
        for (int q = 0; q < 4; ++q) {
            float4 a = qp[q], bb2 = kp[q];
            tq[q * 4 + 0] = __float2bfloat16(a.x); tq[q * 4 + 1] = __float2bfloat16(a.y);
            tq[q * 4 + 2] = __float2bfloat16(a.z); tq[q * 4 + 3] = __float2bfloat16(a.w);
            tk[q * 4 + 0] = __float2bfloat16(bb2.x); tk[q * 4 + 1] = __float2bfloat16(bb2.y);
            tk[q * 4 + 2] = __float2bfloat16(bb2.z); tk[q * 4 + 3] = __float2bfloat16(bb2.w);
        }
        *(uint4*)((char*)Qb + swz(srow, sj0 * 2)) = *(const uint4*)&tq[0];
        *(uint4*)((char*)Qb + swz(srow, sj0 * 2 + 16)) = *(const uint4*)&tq[8];
        *(uint4*)((char*)Knb + swz(srow, sj0 * 2)) = *(const uint4*)&tk[0];
        *(uint4*)((char*)Knb + swz(srow, sj0 * 2 + 16)) = *(const uint4*)&tk[8];
        const uint4* sp = (const uint4*)(Sg + tile + srow * 64 + sj0);
        const uint4* upp = (const uint4*)(Utg + tile + srow * 64 + sj0);
        *(uint4*)((char*)Sbs + swz(srow, sj0 * 2)) = sp[0];
        *(uint4*)((char*)Sbs + swz(srow, sj0 * 2 + 16)) = sp[1];
        *(uint4*)((char*)Utb + swz(srow, sj0 * 2)) = upp[0];
        *(uint4*)((char*)Utb + swz(srow, sj0 * 2 + 16)) = upp[1];
    }
    __syncthreads();

    f32x4 ss[4] = {};
    f32x4 accO[4] = {};
#pragma unroll
    for (int f = 0; f < 2; ++f) {
        bf16x8 qa = ldfrag(Qb, wave, f, lane);
#pragma unroll
        for (int sb = 0; sb < 4; ++sb)
            ss[sb] = __builtin_amdgcn_mfma_f32_16x16x32_bf16(
                qa, ldfrag(Knb, sb, f, lane), ss[sb], 0, 0, 0);
#pragma unroll
        for (int ib = 0; ib < 4; ++ib)
            accO[ib] = __builtin_amdgcn_mfma_f32_16x16x32_bf16(
                qa, ldfrag(Sbs, ib, f, lane), accO[ib], 0, 0, 0);
    }
#pragma unroll
    for (int sb = 0; sb < 4; ++sb)
#pragma unroll
        for (int r = 0; r < 4; ++r) {
            const int t = 16 * wave + (lane >> 4) * 4 + r;
            const int s = 16 * sb + (lane & 15);
            const float v = (t >= s) ? ss[sb][r] : 0.f;
            *(unsigned short*)((char*)SSb + swz(t, s * 2)) = bfbits(v);
        }
    __syncthreads();

#pragma unroll
    for (int f = 0; f < 2; ++f) {
        bf16x8 sa = ldfrag(SSb, wave, f, lane);
#pragma unroll
        for (int ib = 0; ib < 4; ++ib)
            accO[ib] = __builtin_amdgcn_mfma_f32_16x16x32_bf16(
                sa, ldfrag(Utb, ib, f, lane), accO[ib], 0, 0, 0);
    }
#pragma unroll
    for (int ib = 0; ib < 4; ++ib)
#pragma unroll
        for (int r = 0; r < 4; ++r) {
            const int t = 16 * wave + (lane >> 4) * 4 + r;
            const int i = 16 * ib + (lane & 15);
            Qf[gbase + (cOff + t) * gstride + i] = accO[ib][r];
        }
}

// ---------- legacy fp32 GEMM + sequential scan (fallback path only) ----------
#define BM 64
#define BN 64
#define BK 16

template <typename TA, typename TC>
__global__ __launch_bounds__(256) void gemm_kernel(const TA* __restrict__ A,
                                                   const float* __restrict__ B,
                                                   TC* __restrict__ C,
                                                   int M, int N, int K) {
    __shared__ float As[BK][BM + 1];
    __shared__ float Bs[BK][BN + 1];
    const int tid = threadIdx.x;
    const int tr = tid / 16;
    const int tc = tid % 16;
    const int rowBase = blockIdx.y * BM;
    const int colBase = blockIdx.x * BN;

    float acc[4][4];
#pragma unroll
    for (int m = 0; m < 4; ++m)
#pragma unroll
        for (int n = 0; n < 4; ++n) acc[m][n] = 0.f;

    for (int k0 = 0; k0 < K; k0 += BK) {
#pragma unroll
        for (int i = tid; i < BM * BK; i += 256) {
            int r = i / BK, c = i % BK;
            As[c][r] = ldf(&A[(size_t)(rowBase + r) * K + k0 + c]);
        }
#pragma unroll
        for (int i = tid; i < BK * BN; i += 256) {
            int r = i / BN, c = i % BN;
            Bs[r][c] = B[(size_t)(k0 + r) * N + colBase + c];
        }
        __syncthreads();
#pragma unroll
        for (int kk = 0; kk < BK; ++kk) {
            float a[4], b[4];
#pragma unroll
            for (int m = 0; m < 4; ++m) a[m] = As[kk][tr * 4 + m];
#pragma unroll
            for (int n = 0; n < 4; ++n) b[n] = Bs[kk][tc * 4 + n];
#pragma unroll
            for (int m = 0; m < 4; ++m)
#pragma unroll
                for (int n = 0; n < 4; ++n) acc[m][n] += a[m] * b[n];
        }
        __syncthreads();
    }
#pragma unroll
    for (int m = 0; m < 4; ++m)
#pragma unroll
        for (int n = 0; n < 4; ++n)
            stf(&C[(size_t)(rowBase + tr * 4 + m) * N + colBase + tc * 4 + n], acc[m][n]);
}

template <typename TS>
__global__ __launch_bounds__(64) void scan_kernel(const TS* __restrict__ Q,
                                                  const TS* __restrict__ K,
                                                  const TS* __restrict__ V,
                                                  const float* __restrict__ beta,
                                                  float* __restrict__ O) {
    const int bh = blockIdx.x;
    const int b = bh >> 4;
    const int h = bh & 15;
    const int lane = threadIdx.x;

    float Wrow[64];
#pragma unroll
    for (int j = 0; j < 64; ++j) Wrow[j] = 0.f;

    __shared__ float sk[64];
    __shared__ float sq[64];

    size_t base = ((size_t)b * TSEQ) * (NH * DH) + h * DH + lane;
    int brow = b * TSEQ;

    for (int t = 0; t < TSEQ; ++t, base += NH * DH) {
        float k = ldf(&K[base]);
        float q = ldf(&Q[base]);
        float v = ldf(&V[base]);
        float be = beta[(size_t)(brow + t) * NH + h];

        float ss = k * k;
#pragma unroll
        for (int off = 32; off > 0; off >>= 1) ss += __shfl_xor(ss, off);
        k = k / fmaxf(sqrtf(ss), 1e-12f);

        sk[lane] = k;
        sq[lane] = q;
        __syncthreads();

        float p0 = 0.f, p1 = 0.f, p2 = 0.f, p3 = 0.f;
#pragma unroll
        for (int j = 0; j < 64; j += 4) {
            p0 += Wrow[j + 0] * sk[j + 0];
            p1 += Wrow[j + 1] * sk[j + 1];
            p2 += Wrow[j + 2] * sk[j + 2];
            p3 += Wrow[j + 3] * sk[j + 3];
        }
        const float bei = be * (v - ((p0 + p1) + (p2 + p3)));

        float o0 = 0.f, o1 = 0.f, o2 = 0.f, o3 = 0.f;
#pragma unroll
        for (int j = 0; j < 64; j += 4) {
            Wrow[j + 0] += bei * sk[j + 0]; o0 += Wrow[j + 0] * sq[j + 0];
            Wrow[j + 1] += bei * sk[j + 1]; o1 += Wrow[j + 1] * sq[j + 1];
            Wrow[j + 2] += bei * sk[j + 2]; o2 += Wrow[j + 2] * sq[j + 2];
            Wrow[j + 3] += bei * sk[j + 3]; o3 += Wrow[j + 3] * sq[j + 3];
        }
        O[base] = (o0 + o1) + (o2 + o3);
        __syncthreads();
    }
}

// ---------- launch ----------
extern "C" void kernel_launch(void* const* d_in, const int* in_sizes, int n_in,
                              void* d_out, int out_size, void* d_ws, size_t ws_size,
                              hipStream_t stream) {
    const float* x     = (const float*)d_in[0];
    const float* Wq    = (const float*)d_in[1];
    const float* Wk    = (const float*)d_in[2];
    const float* Wv    = (const float*)d_in[3];
    const float* Wbeta = (const float*)d_in[4];
    const float* bbeta = (const float*)d_in[5];
    const float* Wout  = (const float*)d_in[6];
    float* out = (float*)d_out;

    const size_t projElems = (size_t)MROWS * DM;
    const size_t betaBytes = (size_t)MROWS * NH * 4;
    const size_t f32Bytes  = projElems * 4;
    const size_t bf16Bytes = projElems * 2;
    const size_t need_f32  = 4 * f32Bytes + betaBytes;

    char* ws = (char*)d_ws;
    size_t off = 0;
    auto alloc = [&](size_t bytes) {
        char* p = ws + off;
        off += (bytes + 255) & ~(size_t)255;
        return (void*)p;
    };

    if (ws_size >= need_f32) {
        float* Qf = (float*)alloc(f32Bytes);
        float* Kf = (float*)alloc(f32Bytes);
        float* Vf = (float*)alloc(f32Bytes);
        float* Wmf = (float*)alloc(f32Bytes);
        float* betaf = (float*)alloc(betaBytes);

        __hip_bfloat16* xh  = (__hip_bfloat16*)Wmf;
        __hip_bfloat16* WqT = (__hip_bfloat16*)((char*)Wmf + bf16Bytes);
        __hip_bfloat16* WkT = WqT + (size_t)DM * DM;
        __hip_bfloat16* WvT = WkT + (size_t)DM * DM;

        const int n8 = (int)(projElems / 8);
        conv_bf16<<<dim3(n8 / 256), dim3(256), 0, stream>>>(x, xh, n8);
        convT_bf16<<<dim3(16, 16), dim3(256), 0, stream>>>(Wq, WqT);
        convT_bf16<<<dim3(16, 16), dim3(256), 0, stream>>>(Wk, WkT);
        convT_bf16<<<dim3(16, 16), dim3(256), 0, stream>>>(Wv, WvT);

        const dim3 mfmaGrid(DM / 128, MROWS / 128);
        gemm_mfma<<<mfmaGrid, dim3(256), 0, stream>>>(xh, WqT, Qf, MROWS, DM, DM);
        gemm_mfma<<<mfmaGrid, dim3(256), 0, stream>>>(xh, WkT, Kf, MROWS, DM, DM);
        gemm_mfma<<<mfmaGrid, dim3(256), 0, stream>>>(xh, WvT, Vf, MROWS, DM, DM);
        beta_kernel<<<dim3(MROWS / 16), dim3(256), 0, stream>>>(x, Wbeta, bbeta, betaf);

        delta_prepass<<<dim3(NCHUNK, BATCH * NH), dim3(256), 0, stream>>>(Kf, Vf, betaf, Wmf);

        __hip_bfloat16* Sg  = (__hip_bfloat16*)d_out;
        __hip_bfloat16* Utg = Sg + (size_t)BATCH * NH * NCHUNK * 4096;
        scan_thin<<<dim3(BATCH * NH), dim3(256), 0, stream>>>(Kf, Vf, Wmf, Sg, Utg);
        delta_output<<<dim3(NCHUNK, BATCH * NH), dim3(256), 0, stream>>>(Qf, Kf, Sg, Utg);

        __hip_bfloat16* Oh    = (__hip_bfloat16*)Kf;
        __hip_bfloat16* WoutT = (__hip_bfloat16*)((char*)Kf + bf16Bytes);
        conv_bf16<<<dim3(n8 / 256), dim3(256), 0, stream>>>(Qf, Oh, n8);
        convT_bf16<<<dim3(16, 16), dim3(256), 0, stream>>>(Wout, WoutT);
        gemm_mfma<<<mfmaGrid, dim3(256), 0, stream>>>(Oh, WoutT, out, MROWS, DM, DM);
    } else {
        __hip_bfloat16* Qh = (__hip_bfloat16*)alloc(bf16Bytes);
        __hip_bfloat16* Kh = (__hip_bfloat16*)alloc(bf16Bytes);
        __hip_bfloat16* Vh = (__hip_bfloat16*)alloc(bf16Bytes);
        float* betaf = (float*)alloc(betaBytes);
        float* Of = (float*)alloc(f32Bytes);

        const dim3 gemmGrid(DM / BN, MROWS / BM);
        gemm_kernel<float, __hip_bfloat16><<<gemmGrid, dim3(256), 0, stream>>>(x, Wq, Qh, MROWS, DM, DM);
        gemm_kernel<float, __hip_bfloat16><<<gemmGrid, dim3(256), 0, stream>>>(x, Wk, Kh, MROWS, DM, DM);
        gemm_kernel<float, __hip_bfloat16><<<gemmGrid, dim3(256), 0, stream>>>(x, Wv, Vh, MROWS, DM, DM);
        beta_kernel<<<dim3(MROWS / 16), dim3(256), 0, stream>>>(x, Wbeta, bbeta, betaf);
        scan_kernel<__hip_bfloat16><<<dim3(BATCH * NH), dim3(64), 0, stream>>>(Qh, Kh, Vh, betaf, Of);
        gemm_kernel<float, float><<<gemmGrid, dim3(256), 0, stream>>>(Of, Wout, out, MROWS, DM, DM);
    }
}